// Round 10
// baseline (4110.014 us; speedup 1.0000x reference)
//
#include <hip/hip_runtime.h>
#include <hip/hip_bf16.h>

#define MD 1024   // M
#define LD 1024   // L
#define ND 2048   // N
#define JZ 4096   // combined [iou|f] width

typedef __bf16 bf16x8 __attribute__((ext_vector_type(8)));
typedef __bf16 bf16x4 __attribute__((ext_vector_type(4)));
typedef float  f32x4  __attribute__((ext_vector_type(4)));

__device__ __forceinline__ float fsig(float x)  { return 1.0f / (1.0f + __expf(-x)); }
__device__ __forceinline__ float ftanh_(float x){ float e = __expf(2.0f * x); return 1.0f - 2.0f / (e + 1.0f); }

__device__ __forceinline__ bf16x8 bzero8() {
    bf16x8 z;
    #pragma unroll
    for (int q = 0; q < 8; q++) z[q] = (__bf16)0.f;
    return z;
}

// async 16B global -> LDS (dest = wave-uniform base + lane*16)
__device__ __forceinline__ void gload16(const __bf16* g, __bf16* l)
{
    __builtin_amdgcn_global_load_lds(
        (const __attribute__((address_space(1))) void*)g,
        (__attribute__((address_space(3))) void*)l, 16, 0, 0);
}

// ---------------- merged f32 -> bf16 conversions (one launch) ----------------
__global__ void cvt_all_k(const float* __restrict__ iouh_w, const float* __restrict__ fh_w,
                          const float* __restrict__ ioux_w, const float* __restrict__ fx_w,
                          const float* __restrict__ attnh_w, const float* __restrict__ inputs,
                          const float* __restrict__ Hmat,
                          __bf16* __restrict__ WzB, __bf16* __restrict__ WxB,
                          __bf16* __restrict__ W1H, __bf16* __restrict__ W2H,
                          __bf16* __restrict__ inpB, __bf16* __restrict__ HmatB)
{
    const size_t MM = (size_t)MD * MD;
    const size_t b0 = 3 * MM, b1 = 4 * MM, b2 = 7 * MM, b3 = 8 * MM;
    const size_t b4 = 9 * MM, b5 = 10 * MM, b6 = 12 * MM, b7 = 13 * MM;
    for (size_t idx = (size_t)blockIdx.x * 256 + threadIdx.x; idx < b7;
         idx += (size_t)gridDim.x * 256) {
        if (idx < b1) {
            WzB[idx] = (__bf16)((idx < b0) ? iouh_w[idx] : fh_w[idx - b0]);
        } else if (idx < b3) {
            size_t r = idx - b1;
            WxB[r] = (__bf16)((idx < b2) ? ioux_w[r] : fx_w[idx - b2]);
        } else if (idx < b4) {
            size_t r = idx - b3; size_t j = r >> 10, k = r & (MD - 1);
            W1H[r] = (__bf16)attnh_w[j * 2 * MD + k];
        } else if (idx < b5) {
            size_t r = idx - b4; size_t j = r >> 10, k = r & (MD - 1);
            W2H[r] = (__bf16)attnh_w[j * 2 * MD + MD + k];
        } else if (idx < b6) {
            size_t r = idx - b5;
            inpB[r] = (__bf16)inputs[r];
        } else {
            size_t r = idx - b6;
            HmatB[r] = (__bf16)Hmat[r];
        }
    }
}

__global__ void concat_bias_k(const float* __restrict__ a, const float* __restrict__ b,
                              float* __restrict__ dst)
{
    int i = blockIdx.x * 256 + threadIdx.x;
    dst[i] = (i < 3 * MD) ? a[i] : b[i - 3 * MD];
}

// epilogue modes:
//  0: (acc+bias)*scale (+X)
//  1: exp(clamp((acc+bias)*scale (+X), +-80))
//  2: FIN: C = add1[col] - acc + X ; C2 = X - acc ; C3 = bf16(X - acc)
// ---------------- bf16 MFMA NT GEMM, 128x128 tile ----------------
__global__ __launch_bounds__(256) void gemm_mfma(
    const __bf16* __restrict__ Ab, int lda,
    const __bf16* __restrict__ Wh,
    const float* __restrict__ bias,
    const float* __restrict__ X, int ldx, const float* __restrict__ add1,
    float* __restrict__ C, float* __restrict__ C2, __bf16* __restrict__ C3, int ldc,
    int I, int K, float scale, int epi)
{
    __shared__ __align__(16) __bf16 Ash[128][4][8];
    __shared__ __align__(16) __bf16 Bsh[128][4][8];
    const int tid = threadIdx.x;
    const int j0 = blockIdx.x * 128, i0 = blockIdx.y * 128;
    const int lane = tid & 63, wv = tid >> 6;
    const int wm = wv >> 1, wn = wv & 1;
    const int g = lane >> 4, fr = lane & 15;

    f32x4 acc[4][4];
    #pragma unroll
    for (int m = 0; m < 4; m++)
        #pragma unroll
        for (int n = 0; n < 4; n++)
            acc[m][n] = (f32x4){0.f, 0.f, 0.f, 0.f};

    const int srow = tid >> 2;
    const int sg   = tid & 3;
    int ar0 = i0 + srow;       if (ar0 >= I) ar0 = I - 1;
    int ar1 = i0 + srow + 64;  if (ar1 >= I) ar1 = I - 1;
    const __bf16* agp0 = Ab + (size_t)ar0 * lda + sg * 8;
    const __bf16* agp1 = Ab + (size_t)ar1 * lda + sg * 8;
    const __bf16* wgp0 = Wh + (size_t)(j0 + srow) * K + sg * 8;
    const __bf16* wgp1 = Wh + (size_t)(j0 + srow + 64) * K + sg * 8;
    __bf16* aD0 = &Ash[wv * 16][0][0];
    __bf16* aD1 = &Ash[64 + wv * 16][0][0];
    __bf16* bD0 = &Bsh[wv * 16][0][0];
    __bf16* bD1 = &Bsh[64 + wv * 16][0][0];

    for (int kt = 0; kt < K; kt += 32) {
        __syncthreads();
        gload16(agp0 + kt, aD0);
        gload16(agp1 + kt, aD1);
        gload16(wgp0 + kt, bD0);
        gload16(wgp1 + kt, bD1);
        __syncthreads();

        bf16x8 ah[4], bh[4];
        #pragma unroll
        for (int m = 0; m < 4; m++) ah[m] = *(bf16x8*)&Ash[wm * 64 + m * 16 + fr][g][0];
        #pragma unroll
        for (int n = 0; n < 4; n++) bh[n] = *(bf16x8*)&Bsh[wn * 64 + n * 16 + fr][g][0];
        #pragma unroll
        for (int m = 0; m < 4; m++)
            #pragma unroll
            for (int n = 0; n < 4; n++)
                acc[m][n] = __builtin_amdgcn_mfma_f32_16x16x32_bf16(ah[m], bh[n], acc[m][n], 0, 0, 0);
    }

    #pragma unroll
    for (int m = 0; m < 4; m++) {
        int rbase = i0 + wm * 64 + m * 16 + g * 4;
        #pragma unroll
        for (int nn = 0; nn < 4; nn++) {
            int col = j0 + wn * 64 + nn * 16 + fr;
            float b = bias ? bias[col] : 0.f;
            #pragma unroll
            for (int j = 0; j < 4; j++) {
                int r = rbase + j;
                if (r >= I) continue;
                float a = acc[m][nn][j];
                if (epi == 2) {
                    float hc = X[(size_t)r * ldx + col];
                    C[(size_t)r * ldc + col]  = add1[col] - a + hc;
                    float d = hc - a;
                    C2[(size_t)r * ldc + col] = d;
                    C3[(size_t)r * ldc + col] = (__bf16)d;
                } else {
                    float v = (a + b) * scale;
                    if (X) v += X[(size_t)r * ldx + col];
                    if (epi == 1) v = __expf(fminf(fmaxf(v, -80.f), 80.f));
                    C[(size_t)r * ldc + col] = v;
                }
            }
        }
    }
}

// ---------------- bf16 MFMA NT GEMM, 64x64 tile ----------------
__global__ __launch_bounds__(256) void gemm64_mfma(
    const __bf16* __restrict__ Ab, int lda,
    const __bf16* __restrict__ Wh,
    const float* __restrict__ bias,
    const float* __restrict__ X, int ldx, const float* __restrict__ add1,
    float* __restrict__ C, float* __restrict__ C2, __bf16* __restrict__ C3, int ldc,
    int I, int K, float scale, int epi)
{
    __shared__ __align__(16) __bf16 Ash[64][4][8];
    __shared__ __align__(16) __bf16 Bsh[64][4][8];
    const int tid = threadIdx.x;
    const int j0 = blockIdx.x * 64, i0 = blockIdx.y * 64;
    const int lane = tid & 63, wv = tid >> 6;
    const int wm = wv >> 1, wn = wv & 1;
    const int g = lane >> 4, fr = lane & 15;

    f32x4 acc[2][2];
    #pragma unroll
    for (int m = 0; m < 2; m++)
        #pragma unroll
        for (int n = 0; n < 2; n++)
            acc[m][n] = (f32x4){0.f, 0.f, 0.f, 0.f};

    const int srow = tid >> 2;
    const int sg   = tid & 3;
    int ar = i0 + srow;  if (ar >= I) ar = I - 1;
    const __bf16* agp = Ab + (size_t)ar * lda + sg * 8;
    const __bf16* wgp = Wh + (size_t)(j0 + srow) * K + sg * 8;
    __bf16* aD = &Ash[wv * 16][0][0];
    __bf16* bD = &Bsh[wv * 16][0][0];

    for (int kt = 0; kt < K; kt += 32) {
        __syncthreads();
        gload16(agp + kt, aD);
        gload16(wgp + kt, bD);
        __syncthreads();

        bf16x8 ah[2], bh[2];
        #pragma unroll
        for (int m = 0; m < 2; m++) ah[m] = *(bf16x8*)&Ash[wm * 32 + m * 16 + fr][g][0];
        #pragma unroll
        for (int n = 0; n < 2; n++) bh[n] = *(bf16x8*)&Bsh[wn * 32 + n * 16 + fr][g][0];
        #pragma unroll
        for (int m = 0; m < 2; m++)
            #pragma unroll
            for (int n = 0; n < 2; n++)
                acc[m][n] = __builtin_amdgcn_mfma_f32_16x16x32_bf16(ah[m], bh[n], acc[m][n], 0, 0, 0);
    }

    #pragma unroll
    for (int m = 0; m < 2; m++) {
        int rbase = i0 + wm * 32 + m * 16 + g * 4;
        #pragma unroll
        for (int nn = 0; nn < 2; nn++) {
            int col = j0 + wn * 32 + nn * 16 + fr;
            float b = bias ? bias[col] : 0.f;
            #pragma unroll
            for (int j = 0; j < 4; j++) {
                int r = rbase + j;
                if (r >= I) continue;
                float a = acc[m][nn][j];
                if (epi == 2) {
                    float hc = X[(size_t)r * ldx + col];
                    C[(size_t)r * ldc + col]  = add1[col] - a + hc;
                    float d = hc - a;
                    C2[(size_t)r * ldc + col] = d;
                    C3[(size_t)r * ldc + col] = (__bf16)d;
                } else {
                    float v = (a + b) * scale;
                    if (X) v += X[(size_t)r * ldx + col];
                    if (epi == 1) v = __expf(fminf(fmaxf(v, -80.f), 80.f));
                    C[(size_t)r * ldc + col] = v;
                }
            }
        }
    }
}

// ---------------- exact f32 GEMV (HsumWz precompute only) ----------------
template<int IMAX>
__global__ __launch_bounds__(256) void gemv_nt(
    const float* __restrict__ Af, int lda, int I,
    const float* __restrict__ Wf, int ldw,
    float* __restrict__ C, int ldc, int K)
{
    const int wv = threadIdx.x >> 6, lane = threadIdx.x & 63;
    const int j = blockIdx.x * 4 + wv;
    float acc[IMAX];
    #pragma unroll
    for (int i = 0; i < IMAX; i++) acc[i] = 0.0f;
    for (int k = lane * 4; k < K; k += 256) {
        float4 w4 = *(const float4*)(Wf + (size_t)j * ldw + k);
        #pragma unroll
        for (int i = 0; i < IMAX; i++) {
            if (i < I) {
                float4 a4 = *(const float4*)(Af + (size_t)i * lda + k);
                acc[i] += a4.x * w4.x + a4.y * w4.y + a4.z * w4.z + a4.w * w4.w;
            }
        }
    }
    #pragma unroll
    for (int i = 0; i < IMAX; i++) {
        if (i < I) {
            float s = acc[i];
            #pragma unroll
            for (int off = 32; off >= 1; off >>= 1) s += __shfl_xor(s, off);
            if (lane == 0) C[(size_t)i * ldc + j] = s;
        }
    }
}

// ---------------- attention scores via exp tables (mid levels) ----------------
template<int LTILE>
__global__ __launch_bounds__(512) void attn_s(
    int B, const float* __restrict__ Eh,
    const float* __restrict__ EH,
    const float* __restrict__ s_wa_sum,
    const float* __restrict__ Wa,
    float* __restrict__ S)
{
    __shared__ float s_e[8][MD];
    __shared__ float s_wa[MD];
    const int lt = blockIdx.x * LTILE;
    const int b0 = blockIdx.y * 8;
    const int nt = (B - b0 < 8) ? (B - b0) : 8;
    for (int idx = threadIdx.x; idx < MD; idx += 512) s_wa[idx] = Wa[idx];
    for (int i = 0; i < nt; i++)
        for (int idx = threadIdx.x; idx < MD; idx += 512)
            s_e[i][idx] = Eh[(size_t)(b0 + i) * MD + idx];
    __syncthreads();
    const int wv = threadIdx.x >> 6, lane = threadIdx.x & 63;
    const float swa = s_wa_sum[0];
    if (LTILE >= 16) {
        for (int l = lt + wv; l < lt + LTILE; l += 16) {
            float accA[8] = {}, accB[8] = {};
            const float* erA = EH + (size_t)l * MD;
            const float* erB = EH + (size_t)(l + 8) * MD;
            for (int mc = 0; mc < MD; mc += 256) {
                const int m = mc + lane * 4;
                float4 evA = *(const float4*)(erA + m);
                float4 evB = *(const float4*)(erB + m);
                float4 wa4 = *(const float4*)&s_wa[m];
                #pragma unroll
                for (int i = 0; i < 8; i++) {
                    if (i < nt) {
                        float4 se = *(const float4*)&s_e[i][m];
                        accA[i] = fmaf(wa4.x, __builtin_amdgcn_rcpf(fmaf(se.x, evA.x, 1.0f)), accA[i]);
                        accA[i] = fmaf(wa4.y, __builtin_amdgcn_rcpf(fmaf(se.y, evA.y, 1.0f)), accA[i]);
                        accA[i] = fmaf(wa4.z, __builtin_amdgcn_rcpf(fmaf(se.z, evA.z, 1.0f)), accA[i]);
                        accA[i] = fmaf(wa4.w, __builtin_amdgcn_rcpf(fmaf(se.w, evA.w, 1.0f)), accA[i]);
                        accB[i] = fmaf(wa4.x, __builtin_amdgcn_rcpf(fmaf(se.x, evB.x, 1.0f)), accB[i]);
                        accB[i] = fmaf(wa4.y, __builtin_amdgcn_rcpf(fmaf(se.y, evB.y, 1.0f)), accB[i]);
                        accB[i] = fmaf(wa4.z, __builtin_amdgcn_rcpf(fmaf(se.z, evB.z, 1.0f)), accB[i]);
                        accB[i] = fmaf(wa4.w, __builtin_amdgcn_rcpf(fmaf(se.w, evB.w, 1.0f)), accB[i]);
                    }
                }
            }
            #pragma unroll
            for (int i = 0; i < 8; i++) {
                if (i < nt) {
                    float vA = accA[i], vB = accB[i];
                    #pragma unroll
                    for (int off = 32; off >= 1; off >>= 1) {
                        vA += __shfl_xor(vA, off);
                        vB += __shfl_xor(vB, off);
                    }
                    if (lane == 0) {
                        S[(size_t)(b0 + i) * LD + l]     = swa - 2.0f * vA;
                        S[(size_t)(b0 + i) * LD + l + 8] = swa - 2.0f * vB;
                    }
                }
            }
        }
    } else {
        for (int l = lt + wv; l < lt + LTILE; l += 8) {
            float acc[8] = {};
            const float* er = EH + (size_t)l * MD;
            for (int mc = 0; mc < MD; mc += 256) {
                const int m = mc + lane * 4;
                float4 ev  = *(const float4*)(er + m);
                float4 wa4 = *(const float4*)&s_wa[m];
                #pragma unroll
                for (int i = 0; i < 8; i++) {
                    if (i < nt) {
                        float4 se = *(const float4*)&s_e[i][m];
                        acc[i] = fmaf(wa4.x, __builtin_amdgcn_rcpf(fmaf(se.x, ev.x, 1.0f)), acc[i]);
                        acc[i] = fmaf(wa4.y, __builtin_amdgcn_rcpf(fmaf(se.y, ev.y, 1.0f)), acc[i]);
                        acc[i] = fmaf(wa4.z, __builtin_amdgcn_rcpf(fmaf(se.z, ev.z, 1.0f)), acc[i]);
                        acc[i] = fmaf(wa4.w, __builtin_amdgcn_rcpf(fmaf(se.w, ev.w, 1.0f)), acc[i]);
                    }
                }
            }
            #pragma unroll
            for (int i = 0; i < 8; i++) {
                if (i < nt) {
                    float v = acc[i];
                    #pragma unroll
                    for (int off = 32; off >= 1; off >>= 1) v += __shfl_xor(v, off);
                    if (lane == 0) S[(size_t)(b0 + i) * LD + l] = swa - 2.0f * v;
                }
            }
        }
    }
}

// ---------------- softmax (mid levels; f32 + bf16 P) ----------------
__global__ __launch_bounds__(256) void softmax_rows(float* __restrict__ S, __bf16* __restrict__ Sb)
{
    float* row = S + (size_t)blockIdx.x * LD;
    __bf16* rb = Sb + (size_t)blockIdx.x * LD;
    const int tid = threadIdx.x;
    const int wv = tid >> 6, lane = tid & 63;
    float v0 = row[tid], v1 = row[tid + 256], v2 = row[tid + 512], v3 = row[tid + 768];
    float mx = fmaxf(fmaxf(v0, v1), fmaxf(v2, v3));
    #pragma unroll
    for (int off = 32; off >= 1; off >>= 1) mx = fmaxf(mx, __shfl_xor(mx, off));
    __shared__ float r1[4], r2[4];
    if (lane == 0) r1[wv] = mx;
    __syncthreads();
    mx = fmaxf(fmaxf(r1[0], r1[1]), fmaxf(r1[2], r1[3]));
    float e0 = __expf(v0 - mx), e1 = __expf(v1 - mx), e2 = __expf(v2 - mx), e3 = __expf(v3 - mx);
    float sm = e0 + e1 + e2 + e3;
    #pragma unroll
    for (int off = 32; off >= 1; off >>= 1) sm += __shfl_xor(sm, off);
    if (lane == 0) r2[wv] = sm;
    __syncthreads();
    sm = r2[0] + r2[1] + r2[2] + r2[3];
    float inv = 1.0f / sm;
    float p0 = e0 * inv, p1 = e1 * inv, p2 = e2 * inv, p3 = e3 * inv;
    row[tid] = p0; row[tid + 256] = p1; row[tid + 512] = p2; row[tid + 768] = p3;
    rb[tid] = (__bf16)p0; rb[tid + 256] = (__bf16)p1;
    rb[tid + 512] = (__bf16)p2; rb[tid + 768] = (__bf16)p3;
}

// ---------------- cell finish (mid levels) ----------------
__global__ void cell_finish_k(const int* __restrict__ children, int t0,
    const float* __restrict__ Z, const float* __restrict__ HsumWz,
    const float* __restrict__ iouh_b, const float* __restrict__ fh_b,
    const float* __restrict__ x_all,
    float* __restrict__ Cmat, float* __restrict__ hcell, __bf16* __restrict__ hcellB)
{
    int b = blockIdx.y;
    int m = blockIdx.x * 256 + threadIdx.x;
    int t = t0 + b;
    int c0 = children[2 * t], c1 = children[2 * t + 1];
    float cnt = (float)((c0 >= 0) + (c1 >= 0));
    const float* z0 = (c0 >= 0) ? Z + (size_t)c0 * JZ : nullptr;
    const float* z1 = (c1 >= 0) ? Z + (size_t)c1 * JZ : nullptr;
    const float* xr = x_all + (size_t)t * JZ;

    float zi = 0.f, zo = 0.f, zu = 0.f;
    if (z0) { zi += z0[m]; zo += z0[MD + m]; zu += z0[2 * MD + m]; }
    if (z1) { zi += z1[m]; zo += z1[MD + m]; zu += z1[2 * MD + m]; }
    float iv = fsig (zi + cnt * HsumWz[m]           + iouh_b[m]           + xr[m]);
    float ov = fsig (zo + cnt * HsumWz[MD + m]      + iouh_b[MD + m]      + xr[MD + m]);
    float uv = ftanh_(zu + cnt * HsumWz[2 * MD + m] + iouh_b[2 * MD + m]  + xr[2 * MD + m]);

    float hwf = HsumWz[3 * MD + m] + fh_b[m] + xr[3 * MD + m];
    float c = iv * uv;
    if (c0 >= 0) c += fsig(z0[3 * MD + m] + hwf) * Cmat[(size_t)c0 * MD + m];
    if (c1 >= 0) c += fsig(z1[3 * MD + m] + hwf) * Cmat[(size_t)c1 * MD + m];
    Cmat[(size_t)t * MD + m] = c;
    float h = ov * ftanh_(c);
    hcell[(size_t)b * MD + m] = h;
    hcellB[(size_t)b * MD + m] = (__bf16)h;
}

// ---------------- fused tail kernels (levels with B <= 32), NO grid sync ----------------
// tailA: per-block = (l-chunk lc of 128, row b). Computes cell row + Eh row in LDS
// (duplicated per lc; lc==0 writes Cmat/hcell), then S[b][lc*128 .. +128).
__global__ __launch_bounds__(256) void tailA_k(
    const int* __restrict__ children, int t0,
    const float* __restrict__ Zbuf, const float* __restrict__ HsumWz,
    const float* __restrict__ iouh_b, const float* __restrict__ fh_b,
    const float* __restrict__ x_all,
    float* __restrict__ Cmat, float* __restrict__ hcell,
    const __bf16* __restrict__ W1H, const float* __restrict__ EHbuf,
    const float* __restrict__ S_wa, const float* __restrict__ Wa,
    float* __restrict__ Sbuf)
{
    __shared__ float s_h[MD];
    __shared__ float s_e[MD];
    const int lc = blockIdx.x, b = blockIdx.y;
    const int t = t0 + b;
    const int tid = threadIdx.x;
    const int wv = tid >> 6, lane = tid & 63;
    int c0 = children[2 * t], c1 = children[2 * t + 1];
    float cnt = (float)((c0 >= 0) + (c1 >= 0));
    const float* z0 = (c0 >= 0) ? Zbuf + (size_t)c0 * JZ : nullptr;
    const float* z1 = (c1 >= 0) ? Zbuf + (size_t)c1 * JZ : nullptr;
    const float* xr = x_all + (size_t)t * JZ;

    // phase 1: cell row -> s_h
    for (int m = tid; m < MD; m += 256) {
        float zi = 0.f, zo = 0.f, zu = 0.f, zf0 = 0.f, zf1 = 0.f;
        if (z0) { zi += z0[m]; zo += z0[MD + m]; zu += z0[2 * MD + m]; zf0 = z0[3 * MD + m]; }
        if (z1) { zi += z1[m]; zo += z1[MD + m]; zu += z1[2 * MD + m]; zf1 = z1[3 * MD + m]; }
        float iv = fsig (zi + cnt * HsumWz[m]           + iouh_b[m]           + xr[m]);
        float ov = fsig (zo + cnt * HsumWz[MD + m]      + iouh_b[MD + m]      + xr[MD + m]);
        float uv = ftanh_(zu + cnt * HsumWz[2 * MD + m] + iouh_b[2 * MD + m]  + xr[2 * MD + m]);
        float hwf = HsumWz[3 * MD + m] + fh_b[m] + xr[3 * MD + m];
        float c = iv * uv;
        if (c0 >= 0) c += fsig(zf0 + hwf) * Cmat[(size_t)c0 * MD + m];
        if (c1 >= 0) c += fsig(zf1 + hwf) * Cmat[(size_t)c1 * MD + m];
        float h = ov * ftanh_(c);
        s_h[m] = h;
        if (lc == 0) { Cmat[(size_t)t * MD + m] = c; hcell[(size_t)b * MD + m] = h; }
    }
    __syncthreads();
    // phase 2: Eh row -> s_e (wave-per-j)
    for (int j = wv; j < MD; j += 4) {
        const __bf16* Wj = W1H + (size_t)j * MD;
        float a = 0.f;
        for (int k = lane * 4; k < MD; k += 256) {
            bf16x4 w4 = *(const bf16x4*)(Wj + k);
            float4 h4 = *(const float4*)&s_h[k];
            a += h4.x * (float)w4[0] + h4.y * (float)w4[1]
               + h4.z * (float)w4[2] + h4.w * (float)w4[3];
        }
        #pragma unroll
        for (int off = 32; off >= 1; off >>= 1) a += __shfl_xor(a, off);
        if (lane == 0) s_e[j] = __expf(fminf(fmaxf(2.0f * a, -80.f), 80.f));
    }
    __syncthreads();
    // phase 3: S chunk (wave-per-l)
    const float swa = S_wa[0];
    for (int l = lc * 128 + wv; l < lc * 128 + 128; l += 4) {
        const float* er = EHbuf + (size_t)l * MD;
        float a = 0.f;
        for (int m = lane * 4; m < MD; m += 256) {
            float4 ev  = *(const float4*)(er + m);
            float4 se  = *(const float4*)&s_e[m];
            float4 wa4 = *(const float4*)(Wa + m);
            a = fmaf(wa4.x, __builtin_amdgcn_rcpf(fmaf(se.x, ev.x, 1.0f)), a);
            a = fmaf(wa4.y, __builtin_amdgcn_rcpf(fmaf(se.y, ev.y, 1.0f)), a);
            a = fmaf(wa4.z, __builtin_amdgcn_rcpf(fmaf(se.z, ev.z, 1.0f)), a);
            a = fmaf(wa4.w, __builtin_amdgcn_rcpf(fmaf(se.w, ev.w, 1.0f)), a);
        }
        #pragma unroll
        for (int off = 32; off >= 1; off >>= 1) a += __shfl_xor(a, off);
        if (lane == 0) Sbuf[(size_t)b * LD + l] = swa - 2.0f * a;
    }
}

// tailB: per-block = (j-chunk jc of 128, row b). Recomputes softmax of S row into LDS,
// then hpart dots for its j-chunk; emits Hs and Hdelta.
__global__ __launch_bounds__(256) void tailB_k(int t0,
    const float* __restrict__ Sbuf, const __bf16* __restrict__ HtH,
    const float* __restrict__ Hsum, const float* __restrict__ hcell,
    float* __restrict__ Hs, float* __restrict__ Hdelta)
{
    __shared__ float s_p[LD];
    __shared__ float r1[4], r2[4];
    const int jc = blockIdx.x, b = blockIdx.y;
    const int tid = threadIdx.x;
    const int wv = tid >> 6, lane = tid & 63;
    const float* row = Sbuf + (size_t)b * LD;
    float v0 = row[tid], v1 = row[tid + 256], v2 = row[tid + 512], v3 = row[tid + 768];
    float mx = fmaxf(fmaxf(v0, v1), fmaxf(v2, v3));
    #pragma unroll
    for (int off = 32; off >= 1; off >>= 1) mx = fmaxf(mx, __shfl_xor(mx, off));
    if (lane == 0) r1[wv] = mx;
    __syncthreads();
    mx = fmaxf(fmaxf(r1[0], r1[1]), fmaxf(r1[2], r1[3]));
    float e0 = __expf(v0 - mx), e1 = __expf(v1 - mx), e2 = __expf(v2 - mx), e3 = __expf(v3 - mx);
    float sm = e0 + e1 + e2 + e3;
    #pragma unroll
    for (int off = 32; off >= 1; off >>= 1) sm += __shfl_xor(sm, off);
    if (lane == 0) r2[wv] = sm;
    __syncthreads();
    sm = r2[0] + r2[1] + r2[2] + r2[3];
    float inv = 1.0f / sm;
    s_p[tid] = e0 * inv; s_p[tid + 256] = e1 * inv;
    s_p[tid + 512] = e2 * inv; s_p[tid + 768] = e3 * inv;
    __syncthreads();
    for (int j = jc * 128 + wv; j < jc * 128 + 128; j += 4) {
        const __bf16* Hj = HtH + (size_t)j * LD;
        float a = 0.f;
        for (int l = lane * 4; l < LD; l += 256) {
            bf16x4 h4 = *(const bf16x4*)(Hj + l);
            float4 p4 = *(const float4*)&s_p[l];
            a += p4.x * (float)h4[0] + p4.y * (float)h4[1]
               + p4.z * (float)h4[2] + p4.w * (float)h4[3];
        }
        #pragma unroll
        for (int off = 32; off >= 1; off >>= 1) a += __shfl_xor(a, off);
        if (lane == 0) {
            float hc = hcell[(size_t)b * MD + j];
            Hs[(size_t)(t0 + b) * MD + j] = Hsum[j] - a + hc;
            Hdelta[(size_t)(t0 + b) * MD + j] = hc - a;
        }
    }
}

// tailC: per-block = (j-chunk jc of 256 over JZ, row b). Z row = Hdelta row @ Wz^T chunk.
__global__ __launch_bounds__(256) void tailC_k(int t0,
    const float* __restrict__ Hdelta, const __bf16* __restrict__ WzB,
    float* __restrict__ Zbuf)
{
    __shared__ float s_d[MD];
    const int jc = blockIdx.x, b = blockIdx.y;
    const int tid = threadIdx.x;
    const int wv = tid >> 6, lane = tid & 63;
    const float* dr = Hdelta + (size_t)(t0 + b) * MD;
    for (int m = tid; m < MD; m += 256) s_d[m] = dr[m];
    __syncthreads();
    for (int j = jc * 256 + wv; j < jc * 256 + 256; j += 4) {
        const __bf16* Wj = WzB + (size_t)j * MD;
        float a = 0.f;
        for (int k = lane * 4; k < MD; k += 256) {
            bf16x4 w4 = *(const bf16x4*)(Wj + k);
            float4 d4 = *(const float4*)&s_d[k];
            a += d4.x * (float)w4[0] + d4.y * (float)w4[1]
               + d4.z * (float)w4[2] + d4.w * (float)w4[3];
        }
        #pragma unroll
        for (int off = 32; off >= 1; off >>= 1) a += __shfl_xor(a, off);
        if (lane == 0) Zbuf[(size_t)(t0 + b) * JZ + j] = a;
    }
}

// ---------------- misc precompute ----------------
__global__ void colsum_part_k(const float* __restrict__ H, float* __restrict__ part)
{
    int m = blockIdx.x * 256 + threadIdx.x;
    int lb = blockIdx.y;
    float s = 0.f;
    for (int l = lb * 64; l < lb * 64 + 64; l++) s += H[(size_t)l * MD + m];
    part[(size_t)lb * MD + m] = s;
}

__global__ void colsum_reduce_k(const float* __restrict__ part, float* __restrict__ Hsum)
{
    int m = blockIdx.x * 256 + threadIdx.x;
    float s = 0.f;
    for (int lb = 0; lb < 16; lb++) s += part[(size_t)lb * MD + m];
    Hsum[m] = s;
}

__global__ void transpose2_k(const float* __restrict__ H,
                             float* __restrict__ Ht, __bf16* __restrict__ Htb)
{
    __shared__ float tile[32][33];
    int mb = blockIdx.x * 32, lb = blockIdx.y * 32;
    int tx = threadIdx.x, ty = threadIdx.y;
    #pragma unroll
    for (int jj = 0; jj < 4; jj++)
        tile[ty + jj * 8][tx] = H[(size_t)(lb + ty + jj * 8) * MD + mb + tx];
    __syncthreads();
    #pragma unroll
    for (int jj = 0; jj < 4; jj++) {
        float v = tile[tx][ty + jj * 8];
        size_t idx = (size_t)(mb + ty + jj * 8) * LD + lb + tx;
        Ht[idx]  = v;
        Htb[idx] = (__bf16)v;
    }
}

__global__ void sumwa_k(const float* __restrict__ Wa, float* __restrict__ out)
{
    int tid = threadIdx.x;
    float v = Wa[tid] + Wa[tid + 256] + Wa[tid + 512] + Wa[tid + 768];
    #pragma unroll
    for (int off = 32; off >= 1; off >>= 1) v += __shfl_xor(v, off);
    __shared__ float r[4];
    if ((tid & 63) == 0) r[tid >> 6] = v;
    __syncthreads();
    if (tid == 0) out[0] = r[0] + r[1] + r[2] + r[3];
}

__global__ void final_copy_k(const float* __restrict__ Cmat, float* __restrict__ out)
{
    int m = blockIdx.x * 256 + threadIdx.x;
    out[m] = Cmat[m];              // C[0]
    out[1024 + m] = out[2048 + m]; // Hs[0]
}

// ---------------- dispatcher (mid levels; I >= 64) ----------------
static inline void mmx(const __bf16* Ab, int lda, int I,
                       const __bf16* Wb,
                       const float* bias, const float* X, int ldx, const float* add1,
                       float* C, float* C2, __bf16* C3, int ldc, int J, int K,
                       float scale, int epi, hipStream_t s)
{
    int b128 = (J / 128) * ((I + 127) / 128);
    if (b128 >= 192)
        gemm_mfma<<<dim3(J / 128, (I + 127) / 128), 256, 0, s>>>(
            Ab, lda, Wb, bias, X, ldx, add1, C, C2, C3, ldc, I, K, scale, epi);
    else
        gemm64_mfma<<<dim3(J / 64, (I + 63) / 64), 256, 0, s>>>(
            Ab, lda, Wb, bias, X, ldx, add1, C, C2, C3, ldc, I, K, scale, epi);
}

extern "C" void kernel_launch(void* const* d_in, const int* in_sizes, int n_in,
                              void* d_out, int out_size, void* d_ws, size_t ws_size,
                              hipStream_t stream)
{
    const float* inputs   = (const float*)d_in[0];
    const float* Hmat     = (const float*)d_in[1];
    const int*   children = (const int*)d_in[2];
    const float* ioux_w   = (const float*)d_in[3];
    const float* ioux_b   = (const float*)d_in[4];
    const float* iouh_w   = (const float*)d_in[5];
    const float* iouh_b   = (const float*)d_in[6];
    const float* fx_w     = (const float*)d_in[7];
    const float* fx_b     = (const float*)d_in[8];
    const float* fh_w     = (const float*)d_in[9];
    const float* fh_b     = (const float*)d_in[10];
    const float* Wa       = (const float*)d_in[11];
    const float* attnh_w  = (const float*)d_in[12];
    const float* attnh_b  = (const float*)d_in[13];

    float* out = (float*)d_out;
    float* Hs  = out + 2048;   // Hs (N*M) lives in d_out

    // ---- workspace layout ----
    float* p = (float*)d_ws;
    float* x_all   = p;  p += (size_t)ND * JZ;
    float* Zbuf    = p;  p += (size_t)ND * JZ;
    float* EHbuf   = p;  p += (size_t)LD * MD;
    float* Ht      = p;  p += (size_t)MD * LD;
    float* Cmat    = p;  p += (size_t)ND * MD;
    float* Hdelta  = p;  p += (size_t)ND * MD;
    float* hcell   = p;  p += (size_t)1024 * MD;
    float* Ehbuf   = p;  p += (size_t)1024 * MD;
    float* Sbuf    = p;  p += (size_t)1024 * LD;
    float* Hsum    = p;  p += MD;
    float* part16  = p;  p += 16 * MD;
    float* S_wa    = p;  p += 8;
    float* HsumWz  = p;  p += JZ;
    float* bx      = p;  p += JZ;
    __bf16* q = (__bf16*)p;
    __bf16* WzB    = q; q += (size_t)JZ * MD;
    __bf16* WxB    = q; q += (size_t)JZ * MD;
    __bf16* W1H    = q; q += (size_t)MD * MD;
    __bf16* W2H    = q; q += (size_t)MD * MD;
    __bf16* HtH    = q; q += (size_t)MD * LD;
    __bf16* inpB   = q; q += (size_t)ND * MD;
    __bf16* HmatB  = q; q += (size_t)LD * MD;
    __bf16* SbB    = q; q += (size_t)1024 * LD;
    __bf16* HdB    = q; q += (size_t)ND * MD;
    __bf16* hcellB = q; q += (size_t)1024 * MD;

    // ---- one-time conversions & precomputes ----
    cvt_all_k<<<2048, 256, 0, stream>>>(iouh_w, fh_w, ioux_w, fx_w, attnh_w, inputs, Hmat,
                                        WzB, WxB, W1H, W2H, inpB, HmatB);
    concat_bias_k<<<JZ / 256, 256, 0, stream>>>(ioux_b, fx_b, bx);
    transpose2_k<<<dim3(32, 32), dim3(32, 8), 0, stream>>>(Hmat, Ht, HtH);
    sumwa_k<<<1, 256, 0, stream>>>(Wa, S_wa);
    colsum_part_k<<<dim3(4, 16), 256, 0, stream>>>(Hmat, part16);
    colsum_reduce_k<<<4, 256, 0, stream>>>(part16, Hsum);
    gemv_nt<1><<<(3 * MD) / 4, 256, 0, stream>>>(Hsum, MD, 1, iouh_w, MD, HsumWz, 3 * MD, MD);
    gemv_nt<1><<<MD / 4, 256, 0, stream>>>(Hsum, MD, 1, fh_w, MD, HsumWz + 3 * MD, MD, MD);

    // x_all = inputs @ [ioux_w; fx_w]^T + [ioux_b; fx_b]
    mmx(inpB, MD, ND, WxB, bx, nullptr, 0, nullptr,
        x_all, nullptr, nullptr, JZ, JZ, MD, 1.0f, 0, stream);
    // EH = exp(2*(H@W2^T + attnh_b))
    mmx(HmatB, MD, LD, W2H, attnh_b, nullptr, 0, nullptr,
        EHbuf, nullptr, nullptr, MD, MD, MD, 2.0f, 1, stream);

    static const int lv_t0[12] = {2047, 1023, 511, 255, 127, 63, 31, 15, 7, 3, 1, 0};
    static const int lv_B [12] = {1, 1024, 512, 256, 128, 64, 32, 16, 8, 4, 2, 1};

    // ---- level 0 (B=1): fused tail path ----
    {
        int t0 = lv_t0[0], B = lv_B[0];
        tailA_k<<<dim3(8, B), 256, 0, stream>>>(children, t0, Zbuf, HsumWz, iouh_b, fh_b,
                                                x_all, Cmat, hcell, W1H, EHbuf, S_wa, Wa, Sbuf);
        tailB_k<<<dim3(8, B), 256, 0, stream>>>(t0, Sbuf, HtH, Hsum, hcell, Hs, Hdelta);
        tailC_k<<<dim3(16, B), 256, 0, stream>>>(t0, Hdelta, WzB, Zbuf);
    }

    // ---- mid levels (B = 1024..64) ----
    for (int li = 1; li <= 5; li++) {
        int t0 = lv_t0[li], B = lv_B[li];
        cell_finish_k<<<dim3(4, B), 256, 0, stream>>>(children, t0, Zbuf, HsumWz,
                                                      iouh_b, fh_b, x_all, Cmat, hcell, hcellB);
        mmx(hcellB, MD, B, W1H, nullptr, nullptr, 0, nullptr,
            Ehbuf, nullptr, nullptr, MD, MD, MD, 2.0f, 1, stream);
        if (B >= 128)
            attn_s<64><<<dim3(LD / 64, B / 8), 512, 0, stream>>>(B, Ehbuf, EHbuf, S_wa, Wa, Sbuf);
        else
            attn_s<8><<<dim3(LD / 8, (B + 7) / 8), 512, 0, stream>>>(B, Ehbuf, EHbuf, S_wa, Wa, Sbuf);
        softmax_rows<<<B, 256, 0, stream>>>(Sbuf, SbB);
        mmx(SbB, LD, B, HtH, nullptr, hcell, MD, Hsum,
            Hs + (size_t)t0 * MD, Hdelta + (size_t)t0 * MD, HdB + (size_t)t0 * MD,
            MD, MD, LD, 1.0f, 2, stream);
        mmx(HdB + (size_t)t0 * MD, MD, B, WzB, nullptr, nullptr, 0, nullptr,
            Zbuf + (size_t)t0 * JZ, nullptr, nullptr, JZ, JZ, MD, 1.0f, 0, stream);
    }

    // ---- tail levels (B = 32..1): fused 3-kernel path ----
    for (int li = 6; li < 12; li++) {
        int t0 = lv_t0[li], B = lv_B[li];
        tailA_k<<<dim3(8, B), 256, 0, stream>>>(children, t0, Zbuf, HsumWz, iouh_b, fh_b,
                                                x_all, Cmat, hcell, W1H, EHbuf, S_wa, Wa, Sbuf);
        tailB_k<<<dim3(8, B), 256, 0, stream>>>(t0, Sbuf, HtH, Hsum, hcell, Hs, Hdelta);
        if (li != 11)
            tailC_k<<<dim3(16, B), 256, 0, stream>>>(t0, Hdelta, WzB, Zbuf);
    }

    final_copy_k<<<4, 256, 0, stream>>>(Cmat, out);
}

// Round 11
// 1697.995 us; speedup vs baseline: 2.4205x; 2.4205x over previous
//
#include <hip/hip_runtime.h>
#include <hip/hip_bf16.h>

#define MD 1024   // M
#define LD 1024   // L
#define ND 2048   // N
#define JZ 4096   // combined [iou|f] width

typedef __bf16 bf16x8 __attribute__((ext_vector_type(8)));
typedef __bf16 bf16x4 __attribute__((ext_vector_type(4)));
typedef float  f32x4  __attribute__((ext_vector_type(4)));

__device__ __forceinline__ float fsig(float x)  { return 1.0f / (1.0f + __expf(-x)); }
__device__ __forceinline__ float ftanh_(float x){ float e = __expf(2.0f * x); return 1.0f - 2.0f / (e + 1.0f); }

__device__ __forceinline__ bf16x8 bzero8() {
    bf16x8 z;
    #pragma unroll
    for (int q = 0; q < 8; q++) z[q] = (__bf16)0.f;
    return z;
}

// async 16B global -> LDS (dest = wave-uniform base + lane*16)
__device__ __forceinline__ void gload16(const __bf16* g, __bf16* l)
{
    __builtin_amdgcn_global_load_lds(
        (const __attribute__((address_space(1))) void*)g,
        (__attribute__((address_space(3))) void*)l, 16, 0, 0);
}

// ---------------- merged f32 -> bf16 conversions (one launch) ----------------
__global__ void cvt_all_k(const float* __restrict__ iouh_w, const float* __restrict__ fh_w,
                          const float* __restrict__ ioux_w, const float* __restrict__ fx_w,
                          const float* __restrict__ attnh_w, const float* __restrict__ inputs,
                          const float* __restrict__ Hmat,
                          __bf16* __restrict__ WzB, __bf16* __restrict__ WxB,
                          __bf16* __restrict__ W1H, __bf16* __restrict__ W2H,
                          __bf16* __restrict__ inpB, __bf16* __restrict__ HmatB)
{
    const size_t MM = (size_t)MD * MD;
    const size_t b0 = 3 * MM, b1 = 4 * MM, b2 = 7 * MM, b3 = 8 * MM;
    const size_t b4 = 9 * MM, b5 = 10 * MM, b6 = 12 * MM, b7 = 13 * MM;
    for (size_t idx = (size_t)blockIdx.x * 256 + threadIdx.x; idx < b7;
         idx += (size_t)gridDim.x * 256) {
        if (idx < b1) {
            WzB[idx] = (__bf16)((idx < b0) ? iouh_w[idx] : fh_w[idx - b0]);
        } else if (idx < b3) {
            size_t r = idx - b1;
            WxB[r] = (__bf16)((idx < b2) ? ioux_w[r] : fx_w[idx - b2]);
        } else if (idx < b4) {
            size_t r = idx - b3; size_t j = r >> 10, k = r & (MD - 1);
            W1H[r] = (__bf16)attnh_w[j * 2 * MD + k];
        } else if (idx < b5) {
            size_t r = idx - b4; size_t j = r >> 10, k = r & (MD - 1);
            W2H[r] = (__bf16)attnh_w[j * 2 * MD + MD + k];
        } else if (idx < b6) {
            size_t r = idx - b5;
            inpB[r] = (__bf16)inputs[r];
        } else {
            size_t r = idx - b6;
            HmatB[r] = (__bf16)Hmat[r];
        }
    }
}

__global__ void concat_bias_k(const float* __restrict__ a, const float* __restrict__ b,
                              float* __restrict__ dst)
{
    int i = blockIdx.x * 256 + threadIdx.x;
    dst[i] = (i < 3 * MD) ? a[i] : b[i - 3 * MD];
}

// epilogue modes:
//  0: (acc+bias)*scale (+X)
//  1: exp(clamp((acc+bias)*scale (+X), +-80))
//  2: FIN: C = add1[col] - acc + X ; C2 = X - acc ; C3 = bf16(X - acc)
// ---------------- bf16 MFMA NT GEMM, 128x128 tile ----------------
__global__ __launch_bounds__(256) void gemm_mfma(
    const __bf16* __restrict__ Ab, int lda,
    const __bf16* __restrict__ Wh,
    const float* __restrict__ bias,
    const float* __restrict__ X, int ldx, const float* __restrict__ add1,
    float* __restrict__ C, float* __restrict__ C2, __bf16* __restrict__ C3, int ldc,
    int I, int K, float scale, int epi)
{
    __shared__ __align__(16) __bf16 Ash[128][4][8];
    __shared__ __align__(16) __bf16 Bsh[128][4][8];
    const int tid = threadIdx.x;
    const int j0 = blockIdx.x * 128, i0 = blockIdx.y * 128;
    const int lane = tid & 63, wv = tid >> 6;
    const int wm = wv >> 1, wn = wv & 1;
    const int g = lane >> 4, fr = lane & 15;

    f32x4 acc[4][4];
    #pragma unroll
    for (int m = 0; m < 4; m++)
        #pragma unroll
        for (int n = 0; n < 4; n++)
            acc[m][n] = (f32x4){0.f, 0.f, 0.f, 0.f};

    const int srow = tid >> 2;
    const int sg   = tid & 3;
    int ar0 = i0 + srow;       if (ar0 >= I) ar0 = I - 1;
    int ar1 = i0 + srow + 64;  if (ar1 >= I) ar1 = I - 1;
    const __bf16* agp0 = Ab + (size_t)ar0 * lda + sg * 8;
    const __bf16* agp1 = Ab + (size_t)ar1 * lda + sg * 8;
    const __bf16* wgp0 = Wh + (size_t)(j0 + srow) * K + sg * 8;
    const __bf16* wgp1 = Wh + (size_t)(j0 + srow + 64) * K + sg * 8;
    __bf16* aD0 = &Ash[wv * 16][0][0];
    __bf16* aD1 = &Ash[64 + wv * 16][0][0];
    __bf16* bD0 = &Bsh[wv * 16][0][0];
    __bf16* bD1 = &Bsh[64 + wv * 16][0][0];

    for (int kt = 0; kt < K; kt += 32) {
        __syncthreads();
        gload16(agp0 + kt, aD0);
        gload16(agp1 + kt, aD1);
        gload16(wgp0 + kt, bD0);
        gload16(wgp1 + kt, bD1);
        __syncthreads();

        bf16x8 ah[4], bh[4];
        #pragma unroll
        for (int m = 0; m < 4; m++) ah[m] = *(bf16x8*)&Ash[wm * 64 + m * 16 + fr][g][0];
        #pragma unroll
        for (int n = 0; n < 4; n++) bh[n] = *(bf16x8*)&Bsh[wn * 64 + n * 16 + fr][g][0];
        #pragma unroll
        for (int m = 0; m < 4; m++)
            #pragma unroll
            for (int n = 0; n < 4; n++)
                acc[m][n] = __builtin_amdgcn_mfma_f32_16x16x32_bf16(ah[m], bh[n], acc[m][n], 0, 0, 0);
    }

    #pragma unroll
    for (int m = 0; m < 4; m++) {
        int rbase = i0 + wm * 64 + m * 16 + g * 4;
        #pragma unroll
        for (int nn = 0; nn < 4; nn++) {
            int col = j0 + wn * 64 + nn * 16 + fr;
            float b = bias ? bias[col] : 0.f;
            #pragma unroll
            for (int j = 0; j < 4; j++) {
                int r = rbase + j;
                if (r >= I) continue;
                float a = acc[m][nn][j];
                if (epi == 2) {
                    float hc = X[(size_t)r * ldx + col];
                    C[(size_t)r * ldc + col]  = add1[col] - a + hc;
                    float d = hc - a;
                    C2[(size_t)r * ldc + col] = d;
                    C3[(size_t)r * ldc + col] = (__bf16)d;
                } else {
                    float v = (a + b) * scale;
                    if (X) v += X[(size_t)r * ldx + col];
                    if (epi == 1) v = __expf(fminf(fmaxf(v, -80.f), 80.f));
                    C[(size_t)r * ldc + col] = v;
                }
            }
        }
    }
}

// ---------------- bf16 MFMA NT GEMM, 64x64 tile ----------------
__global__ __launch_bounds__(256) void gemm64_mfma(
    const __bf16* __restrict__ Ab, int lda,
    const __bf16* __restrict__ Wh,
    const float* __restrict__ bias,
    const float* __restrict__ X, int ldx, const float* __restrict__ add1,
    float* __restrict__ C, float* __restrict__ C2, __bf16* __restrict__ C3, int ldc,
    int I, int K, float scale, int epi)
{
    __shared__ __align__(16) __bf16 Ash[64][4][8];
    __shared__ __align__(16) __bf16 Bsh[64][4][8];
    const int tid = threadIdx.x;
    const int j0 = blockIdx.x * 64, i0 = blockIdx.y * 64;
    const int lane = tid & 63, wv = tid >> 6;
    const int wm = wv >> 1, wn = wv & 1;
    const int g = lane >> 4, fr = lane & 15;

    f32x4 acc[2][2];
    #pragma unroll
    for (int m = 0; m < 2; m++)
        #pragma unroll
        for (int n = 0; n < 2; n++)
            acc[m][n] = (f32x4){0.f, 0.f, 0.f, 0.f};

    const int srow = tid >> 2;
    const int sg   = tid & 3;
    int ar = i0 + srow;  if (ar >= I) ar = I - 1;
    const __bf16* agp = Ab + (size_t)ar * lda + sg * 8;
    const __bf16* wgp = Wh + (size_t)(j0 + srow) * K + sg * 8;
    __bf16* aD = &Ash[wv * 16][0][0];
    __bf16* bD = &Bsh[wv * 16][0][0];

    for (int kt = 0; kt < K; kt += 32) {
        __syncthreads();
        gload16(agp + kt, aD);
        gload16(wgp + kt, bD);
        __syncthreads();

        bf16x8 ah[2], bh[2];
        #pragma unroll
        for (int m = 0; m < 2; m++) ah[m] = *(bf16x8*)&Ash[wm * 32 + m * 16 + fr][g][0];
        #pragma unroll
        for (int n = 0; n < 2; n++) bh[n] = *(bf16x8*)&Bsh[wn * 32 + n * 16 + fr][g][0];
        #pragma unroll
        for (int m = 0; m < 2; m++)
            #pragma unroll
            for (int n = 0; n < 2; n++)
                acc[m][n] = __builtin_amdgcn_mfma_f32_16x16x32_bf16(ah[m], bh[n], acc[m][n], 0, 0, 0);
    }

    #pragma unroll
    for (int m = 0; m < 2; m++) {
        int rbase = i0 + wm * 32 + m * 16 + g * 4;
        #pragma unroll
        for (int nn = 0; nn < 2; nn++) {
            int col = j0 + wn * 32 + nn * 16 + fr;
            float b = bias ? bias[col] : 0.f;
            #pragma unroll
            for (int j = 0; j < 4; j++) {
                int r = rbase + j;
                if (r >= I) continue;
                float a = acc[m][nn][j];
                if (epi == 2) {
                    float hc = X[(size_t)r * ldx + col];
                    C[(size_t)r * ldc + col]  = add1[col] - a + hc;
                    float d = hc - a;
                    C2[(size_t)r * ldc + col] = d;
                    C3[(size_t)r * ldc + col] = (__bf16)d;
                } else {
                    float v = (a + b) * scale;
                    if (X) v += X[(size_t)r * ldx + col];
                    if (epi == 1) v = __expf(fminf(fmaxf(v, -80.f), 80.f));
                    C[(size_t)r * ldc + col] = v;
                }
            }
        }
    }
}

// ---------------- i-tiled batched GEMV (f32 A x bf16 W), grid (J/4, ceil(I/16)) ----------------
__global__ __launch_bounds__(256) void gemv16(
    const float* __restrict__ Af, int lda, int I,
    const __bf16* __restrict__ Wb, int ldw,
    const float* __restrict__ bias,
    const float* __restrict__ X, int ldx, const float* __restrict__ add1,
    float* __restrict__ C, float* __restrict__ C2, __bf16* __restrict__ C3, int ldc,
    int K, float scale, int epi)
{
    const int wv = threadIdx.x >> 6, lane = threadIdx.x & 63;
    const int j = blockIdx.x * 4 + wv;
    const int i0 = blockIdx.y * 16;
    const int nI = (I - i0 < 16) ? (I - i0) : 16;
    float acc[16];
    #pragma unroll
    for (int i = 0; i < 16; i++) acc[i] = 0.0f;
    const __bf16* Wj = Wb + (size_t)j * ldw;
    for (int k = lane * 4; k < K; k += 256) {
        bf16x4 w4 = *(const bf16x4*)(Wj + k);
        float w0 = (float)w4[0], w1 = (float)w4[1], w2 = (float)w4[2], w3 = (float)w4[3];
        #pragma unroll
        for (int i = 0; i < 16; i++) {
            if (i < nI) {
                float4 a4 = *(const float4*)(Af + (size_t)(i0 + i) * lda + k);
                acc[i] += a4.x * w0 + a4.y * w1 + a4.z * w2 + a4.w * w3;
            }
        }
    }
    #pragma unroll
    for (int i = 0; i < 16; i++) {
        if (i < nI) {
            float s = acc[i];
            #pragma unroll
            for (int off = 32; off >= 1; off >>= 1) s += __shfl_xor(s, off);
            if (lane == 0) {
                int r = i0 + i;
                if (epi == 2) {
                    float hc = X[(size_t)r * ldx + j];
                    C[(size_t)r * ldc + j]  = add1[j] - s + hc;
                    float d = hc - s;
                    C2[(size_t)r * ldc + j] = d;
                    C3[(size_t)r * ldc + j] = (__bf16)d;
                } else {
                    float v = (s + (bias ? bias[j] : 0.f)) * scale;
                    if (X) v += X[(size_t)r * ldx + j];
                    if (epi == 1) v = __expf(fminf(fmaxf(v, -80.f), 80.f));
                    C[(size_t)r * ldc + j] = v;
                }
            }
        }
    }
}

// ---------------- exact f32 GEMV (HsumWz precompute only, I=1) ----------------
__global__ __launch_bounds__(256) void gemvHsum(
    const float* __restrict__ Af,
    const float* __restrict__ Wf, int ldw,
    float* __restrict__ C, int K)
{
    const int wv = threadIdx.x >> 6, lane = threadIdx.x & 63;
    const int j = blockIdx.x * 4 + wv;
    float a = 0.f;
    for (int k = lane * 4; k < K; k += 256) {
        float4 w4 = *(const float4*)(Wf + (size_t)j * ldw + k);
        float4 a4 = *(const float4*)(Af + k);
        a += a4.x * w4.x + a4.y * w4.y + a4.z * w4.z + a4.w * w4.w;
    }
    #pragma unroll
    for (int off = 32; off >= 1; off >>= 1) a += __shfl_xor(a, off);
    if (lane == 0) C[j] = a;
}

// ---------------- attention scores via exp tables ----------------
template<int LTILE>
__global__ __launch_bounds__(512) void attn_s(
    int B, const float* __restrict__ Eh,
    const float* __restrict__ EH,
    const float* __restrict__ s_wa_sum,
    const float* __restrict__ Wa,
    float* __restrict__ S)
{
    __shared__ float s_e[8][MD];
    __shared__ float s_wa[MD];
    const int lt = blockIdx.x * LTILE;
    const int b0 = blockIdx.y * 8;
    const int nt = (B - b0 < 8) ? (B - b0) : 8;
    for (int idx = threadIdx.x; idx < MD; idx += 512) s_wa[idx] = Wa[idx];
    for (int i = 0; i < nt; i++)
        for (int idx = threadIdx.x; idx < MD; idx += 512)
            s_e[i][idx] = Eh[(size_t)(b0 + i) * MD + idx];
    __syncthreads();
    const int wv = threadIdx.x >> 6, lane = threadIdx.x & 63;
    const float swa = s_wa_sum[0];
    if (LTILE >= 16) {
        for (int l = lt + wv; l < lt + LTILE; l += 16) {
            float accA[8] = {}, accB[8] = {};
            const float* erA = EH + (size_t)l * MD;
            const float* erB = EH + (size_t)(l + 8) * MD;
            for (int mc = 0; mc < MD; mc += 256) {
                const int m = mc + lane * 4;
                float4 evA = *(const float4*)(erA + m);
                float4 evB = *(const float4*)(erB + m);
                float4 wa4 = *(const float4*)&s_wa[m];
                #pragma unroll
                for (int i = 0; i < 8; i++) {
                    if (i < nt) {
                        float4 se = *(const float4*)&s_e[i][m];
                        accA[i] = fmaf(wa4.x, __builtin_amdgcn_rcpf(fmaf(se.x, evA.x, 1.0f)), accA[i]);
                        accA[i] = fmaf(wa4.y, __builtin_amdgcn_rcpf(fmaf(se.y, evA.y, 1.0f)), accA[i]);
                        accA[i] = fmaf(wa4.z, __builtin_amdgcn_rcpf(fmaf(se.z, evA.z, 1.0f)), accA[i]);
                        accA[i] = fmaf(wa4.w, __builtin_amdgcn_rcpf(fmaf(se.w, evA.w, 1.0f)), accA[i]);
                        accB[i] = fmaf(wa4.x, __builtin_amdgcn_rcpf(fmaf(se.x, evB.x, 1.0f)), accB[i]);
                        accB[i] = fmaf(wa4.y, __builtin_amdgcn_rcpf(fmaf(se.y, evB.y, 1.0f)), accB[i]);
                        accB[i] = fmaf(wa4.z, __builtin_amdgcn_rcpf(fmaf(se.z, evB.z, 1.0f)), accB[i]);
                        accB[i] = fmaf(wa4.w, __builtin_amdgcn_rcpf(fmaf(se.w, evB.w, 1.0f)), accB[i]);
                    }
                }
            }
            #pragma unroll
            for (int i = 0; i < 8; i++) {
                if (i < nt) {
                    float vA = accA[i], vB = accB[i];
                    #pragma unroll
                    for (int off = 32; off >= 1; off >>= 1) {
                        vA += __shfl_xor(vA, off);
                        vB += __shfl_xor(vB, off);
                    }
                    if (lane == 0) {
                        S[(size_t)(b0 + i) * LD + l]     = swa - 2.0f * vA;
                        S[(size_t)(b0 + i) * LD + l + 8] = swa - 2.0f * vB;
                    }
                }
            }
        }
    } else {
        for (int l = lt + wv; l < lt + LTILE; l += 8) {
            float acc[8] = {};
            const float* er = EH + (size_t)l * MD;
            for (int mc = 0; mc < MD; mc += 256) {
                const int m = mc + lane * 4;
                float4 ev  = *(const float4*)(er + m);
                float4 wa4 = *(const float4*)&s_wa[m];
                #pragma unroll
                for (int i = 0; i < 8; i++) {
                    if (i < nt) {
                        float4 se = *(const float4*)&s_e[i][m];
                        acc[i] = fmaf(wa4.x, __builtin_amdgcn_rcpf(fmaf(se.x, ev.x, 1.0f)), acc[i]);
                        acc[i] = fmaf(wa4.y, __builtin_amdgcn_rcpf(fmaf(se.y, ev.y, 1.0f)), acc[i]);
                        acc[i] = fmaf(wa4.z, __builtin_amdgcn_rcpf(fmaf(se.z, ev.z, 1.0f)), acc[i]);
                        acc[i] = fmaf(wa4.w, __builtin_amdgcn_rcpf(fmaf(se.w, ev.w, 1.0f)), acc[i]);
                    }
                }
            }
            #pragma unroll
            for (int i = 0; i < 8; i++) {
                if (i < nt) {
                    float v = acc[i];
                    #pragma unroll
                    for (int off = 32; off >= 1; off >>= 1) v += __shfl_xor(v, off);
                    if (lane == 0) S[(size_t)(b0 + i) * LD + l] = swa - 2.0f * v;
                }
            }
        }
    }
}

// ---------------- softmax (f32 + bf16 copies of P) ----------------
__global__ __launch_bounds__(256) void softmax_rows(float* __restrict__ S, __bf16* __restrict__ Sb)
{
    float* row = S + (size_t)blockIdx.x * LD;
    __bf16* rb = Sb + (size_t)blockIdx.x * LD;
    const int tid = threadIdx.x;
    const int wv = tid >> 6, lane = tid & 63;
    float v0 = row[tid], v1 = row[tid + 256], v2 = row[tid + 512], v3 = row[tid + 768];
    float mx = fmaxf(fmaxf(v0, v1), fmaxf(v2, v3));
    #pragma unroll
    for (int off = 32; off >= 1; off >>= 1) mx = fmaxf(mx, __shfl_xor(mx, off));
    __shared__ float r1[4], r2[4];
    if (lane == 0) r1[wv] = mx;
    __syncthreads();
    mx = fmaxf(fmaxf(r1[0], r1[1]), fmaxf(r1[2], r1[3]));
    float e0 = __expf(v0 - mx), e1 = __expf(v1 - mx), e2 = __expf(v2 - mx), e3 = __expf(v3 - mx);
    float sm = e0 + e1 + e2 + e3;
    #pragma unroll
    for (int off = 32; off >= 1; off >>= 1) sm += __shfl_xor(sm, off);
    if (lane == 0) r2[wv] = sm;
    __syncthreads();
    sm = r2[0] + r2[1] + r2[2] + r2[3];
    float inv = 1.0f / sm;
    float p0 = e0 * inv, p1 = e1 * inv, p2 = e2 * inv, p3 = e3 * inv;
    row[tid] = p0; row[tid + 256] = p1; row[tid + 512] = p2; row[tid + 768] = p3;
    rb[tid] = (__bf16)p0; rb[tid + 256] = (__bf16)p1;
    rb[tid + 512] = (__bf16)p2; rb[tid + 768] = (__bf16)p3;
}

// ---------------- cell finish ----------------
__global__ void cell_finish_k(const int* __restrict__ children, int t0,
    const float* __restrict__ Z, const float* __restrict__ HsumWz,
    const float* __restrict__ iouh_b, const float* __restrict__ fh_b,
    const float* __restrict__ x_all,
    float* __restrict__ Cmat, float* __restrict__ hcell, __bf16* __restrict__ hcellB)
{
    int b = blockIdx.y;
    int m = blockIdx.x * 256 + threadIdx.x;
    int t = t0 + b;
    int c0 = children[2 * t], c1 = children[2 * t + 1];
    float cnt = (float)((c0 >= 0) + (c1 >= 0));
    const float* z0 = (c0 >= 0) ? Z + (size_t)c0 * JZ : nullptr;
    const float* z1 = (c1 >= 0) ? Z + (size_t)c1 * JZ : nullptr;
    const float* xr = x_all + (size_t)t * JZ;

    float zi = 0.f, zo = 0.f, zu = 0.f;
    if (z0) { zi += z0[m]; zo += z0[MD + m]; zu += z0[2 * MD + m]; }
    if (z1) { zi += z1[m]; zo += z1[MD + m]; zu += z1[2 * MD + m]; }
    float iv = fsig (zi + cnt * HsumWz[m]           + iouh_b[m]           + xr[m]);
    float ov = fsig (zo + cnt * HsumWz[MD + m]      + iouh_b[MD + m]      + xr[MD + m]);
    float uv = ftanh_(zu + cnt * HsumWz[2 * MD + m] + iouh_b[2 * MD + m]  + xr[2 * MD + m]);

    float hwf = HsumWz[3 * MD + m] + fh_b[m] + xr[3 * MD + m];
    float c = iv * uv;
    if (c0 >= 0) c += fsig(z0[3 * MD + m] + hwf) * Cmat[(size_t)c0 * MD + m];
    if (c1 >= 0) c += fsig(z1[3 * MD + m] + hwf) * Cmat[(size_t)c1 * MD + m];
    Cmat[(size_t)t * MD + m] = c;
    float h = ov * ftanh_(c);
    hcell[(size_t)b * MD + m] = h;
    hcellB[(size_t)b * MD + m] = (__bf16)h;
}

// ---------------- misc precompute ----------------
__global__ void colsum_part_k(const float* __restrict__ H, float* __restrict__ part)
{
    int m = blockIdx.x * 256 + threadIdx.x;
    int lb = blockIdx.y;
    float s = 0.f;
    for (int l = lb * 64; l < lb * 64 + 64; l++) s += H[(size_t)l * MD + m];
    part[(size_t)lb * MD + m] = s;
}

__global__ void colsum_reduce_k(const float* __restrict__ part, float* __restrict__ Hsum)
{
    int m = blockIdx.x * 256 + threadIdx.x;
    float s = 0.f;
    for (int lb = 0; lb < 16; lb++) s += part[(size_t)lb * MD + m];
    Hsum[m] = s;
}

__global__ void transpose2_k(const float* __restrict__ H,
                             float* __restrict__ Ht, __bf16* __restrict__ Htb)
{
    __shared__ float tile[32][33];
    int mb = blockIdx.x * 32, lb = blockIdx.y * 32;
    int tx = threadIdx.x, ty = threadIdx.y;
    #pragma unroll
    for (int jj = 0; jj < 4; jj++)
        tile[ty + jj * 8][tx] = H[(size_t)(lb + ty + jj * 8) * MD + mb + tx];
    __syncthreads();
    #pragma unroll
    for (int jj = 0; jj < 4; jj++) {
        float v = tile[tx][ty + jj * 8];
        size_t idx = (size_t)(mb + ty + jj * 8) * LD + lb + tx;
        Ht[idx]  = v;
        Htb[idx] = (__bf16)v;
    }
}

__global__ void sumwa_k(const float* __restrict__ Wa, float* __restrict__ out)
{
    int tid = threadIdx.x;
    float v = Wa[tid] + Wa[tid + 256] + Wa[tid + 512] + Wa[tid + 768];
    #pragma unroll
    for (int off = 32; off >= 1; off >>= 1) v += __shfl_xor(v, off);
    __shared__ float r[4];
    if ((tid & 63) == 0) r[tid >> 6] = v;
    __syncthreads();
    if (tid == 0) out[0] = r[0] + r[1] + r[2] + r[3];
}

__global__ void final_copy_k(const float* __restrict__ Cmat, float* __restrict__ out)
{
    int m = blockIdx.x * 256 + threadIdx.x;
    out[m] = Cmat[m];              // C[0]
    out[1024 + m] = out[2048 + m]; // Hs[0]
}

// ---------------- dispatcher ----------------
static inline void mmx(const __bf16* Ab, const float* Af, int lda, int I,
                       const __bf16* Wb,
                       const float* bias, const float* X, int ldx, const float* add1,
                       float* C, float* C2, __bf16* C3, int ldc, int J, int K,
                       float scale, int epi, hipStream_t s)
{
    if (I <= 256) {
        gemv16<<<dim3(J / 4, (I + 15) / 16), 256, 0, s>>>(
            Af, lda, I, Wb, K, bias, X, ldx, add1, C, C2, C3, ldc, K, scale, epi);
    } else {
        int b128 = (J / 128) * ((I + 127) / 128);
        if (b128 >= 192)
            gemm_mfma<<<dim3(J / 128, (I + 127) / 128), 256, 0, s>>>(
                Ab, lda, Wb, bias, X, ldx, add1, C, C2, C3, ldc, I, K, scale, epi);
        else
            gemm64_mfma<<<dim3(J / 64, (I + 63) / 64), 256, 0, s>>>(
                Ab, lda, Wb, bias, X, ldx, add1, C, C2, C3, ldc, I, K, scale, epi);
    }
}

extern "C" void kernel_launch(void* const* d_in, const int* in_sizes, int n_in,
                              void* d_out, int out_size, void* d_ws, size_t ws_size,
                              hipStream_t stream)
{
    const float* inputs   = (const float*)d_in[0];
    const float* Hmat     = (const float*)d_in[1];
    const int*   children = (const int*)d_in[2];
    const float* ioux_w   = (const float*)d_in[3];
    const float* ioux_b   = (const float*)d_in[4];
    const float* iouh_w   = (const float*)d_in[5];
    const float* iouh_b   = (const float*)d_in[6];
    const float* fx_w     = (const float*)d_in[7];
    const float* fx_b     = (const float*)d_in[8];
    const float* fh_w     = (const float*)d_in[9];
    const float* fh_b     = (const float*)d_in[10];
    const float* Wa       = (const float*)d_in[11];
    const float* attnh_w  = (const float*)d_in[12];
    const float* attnh_b  = (const float*)d_in[13];

    float* out = (float*)d_out;
    float* Hs  = out + 2048;   // Hs (N*M) lives in d_out

    // ---- workspace layout ----
    float* p = (float*)d_ws;
    float* x_all   = p;  p += (size_t)ND * JZ;
    float* Zbuf    = p;  p += (size_t)ND * JZ;
    float* EHbuf   = p;  p += (size_t)LD * MD;
    float* Ht      = p;  p += (size_t)MD * LD;
    float* Cmat    = p;  p += (size_t)ND * MD;
    float* Hdelta  = p;  p += (size_t)ND * MD;
    float* hcell   = p;  p += (size_t)1024 * MD;
    float* Ehbuf   = p;  p += (size_t)1024 * MD;
    float* Sbuf    = p;  p += (size_t)1024 * LD;
    float* Hsum    = p;  p += MD;
    float* part16  = p;  p += 16 * MD;
    float* S_wa    = p;  p += 8;
    float* HsumWz  = p;  p += JZ;
    float* bx      = p;  p += JZ;
    __bf16* q = (__bf16*)p;
    __bf16* WzB    = q; q += (size_t)JZ * MD;
    __bf16* WxB    = q; q += (size_t)JZ * MD;
    __bf16* W1H    = q; q += (size_t)MD * MD;
    __bf16* W2H    = q; q += (size_t)MD * MD;
    __bf16* HtH    = q; q += (size_t)MD * LD;
    __bf16* inpB   = q; q += (size_t)ND * MD;
    __bf16* HmatB  = q; q += (size_t)LD * MD;
    __bf16* SbB    = q; q += (size_t)1024 * LD;
    __bf16* HdB    = q; q += (size_t)ND * MD;
    __bf16* hcellB = q; q += (size_t)1024 * MD;

    // ---- one-time conversions & precomputes ----
    cvt_all_k<<<2048, 256, 0, stream>>>(iouh_w, fh_w, ioux_w, fx_w, attnh_w, inputs, Hmat,
                                        WzB, WxB, W1H, W2H, inpB, HmatB);
    concat_bias_k<<<JZ / 256, 256, 0, stream>>>(ioux_b, fx_b, bx);
    transpose2_k<<<dim3(32, 32), dim3(32, 8), 0, stream>>>(Hmat, Ht, HtH);
    sumwa_k<<<1, 256, 0, stream>>>(Wa, S_wa);
    colsum_part_k<<<dim3(4, 16), 256, 0, stream>>>(Hmat, part16);
    colsum_reduce_k<<<4, 256, 0, stream>>>(part16, Hsum);
    gemvHsum<<<(3 * MD) / 4, 256, 0, stream>>>(Hsum, iouh_w, MD, HsumWz, MD);
    gemvHsum<<<MD / 4, 256, 0, stream>>>(Hsum, fh_w, MD, HsumWz + 3 * MD, MD);

    // x_all = inputs @ [ioux_w; fx_w]^T + [ioux_b; fx_b]
    mmx(inpB, inputs, MD, ND, WxB, bx, nullptr, 0, nullptr,
        x_all, nullptr, nullptr, JZ, JZ, MD, 1.0f, 0, stream);
    // EH = exp(2*(H@W2^T + attnh_b))
    mmx(HmatB, Hmat, MD, LD, W2H, attnh_b, nullptr, 0, nullptr,
        EHbuf, nullptr, nullptr, MD, MD, MD, 2.0f, 1, stream);

    static const int lv_t0[12] = {2047, 1023, 511, 255, 127, 63, 31, 15, 7, 3, 1, 0};
    static const int lv_B [12] = {1, 1024, 512, 256, 128, 64, 32, 16, 8, 4, 2, 1};

    // ---- level-parallel tree scan (deepest first), uniform 6-kernel pipeline ----
    for (int li = 0; li < 12; li++) {
        int t0 = lv_t0[li], B = lv_B[li];
        cell_finish_k<<<dim3(4, B), 256, 0, stream>>>(children, t0, Zbuf, HsumWz,
                                                      iouh_b, fh_b, x_all, Cmat, hcell, hcellB);
        // Eh = exp(2*hcell@W1^T)
        mmx(hcellB, hcell, MD, B, W1H, nullptr, nullptr, 0, nullptr,
            Ehbuf, nullptr, nullptr, MD, MD, MD, 2.0f, 1, stream);
        if (B >= 128)
            attn_s<64><<<dim3(LD / 64, B / 8), 512, 0, stream>>>(B, Ehbuf, EHbuf, S_wa, Wa, Sbuf);
        else if (B >= 16)
            attn_s<16><<<dim3(LD / 16, (B + 7) / 8), 512, 0, stream>>>(B, Ehbuf, EHbuf, S_wa, Wa, Sbuf);
        else
            attn_s<8><<<dim3(LD / 8, 1), 512, 0, stream>>>(B, Ehbuf, EHbuf, S_wa, Wa, Sbuf);
        softmax_rows<<<B, 256, 0, stream>>>(Sbuf, SbB);
        // FIN: Hs = Hsum - p@H + hcell ; Hdelta/HdB = hcell - p@H
        mmx(SbB, Sbuf, LD, B, HtH, nullptr, hcell, MD, Hsum,
            Hs + (size_t)t0 * MD, Hdelta + (size_t)t0 * MD, HdB + (size_t)t0 * MD,
            MD, MD, LD, 1.0f, 2, stream);
        // Z[t] = Hdelta[t] @ [iouh_w; fh_w]^T  (not needed for root)
        if (li < 11)
            mmx(HdB + (size_t)t0 * MD, Hdelta + (size_t)t0 * MD, MD, B, WzB,
                nullptr, nullptr, 0, nullptr,
                Zbuf + (size_t)t0 * JZ, nullptr, nullptr, JZ, JZ, MD, 1.0f, 0, stream);
    }
    final_copy_k<<<4, 256, 0, stream>>>(Cmat, out);
}

// Round 12
// 1144.970 us; speedup vs baseline: 3.5896x; 1.4830x over previous
//
#include <hip/hip_runtime.h>
#include <hip/hip_bf16.h>

#define MD 1024   // M
#define LD 1024   // L
#define ND 2048   // N
#define JZ 4096   // combined [iou|f] width

typedef __bf16 bf16x8 __attribute__((ext_vector_type(8)));
typedef __bf16 bf16x4 __attribute__((ext_vector_type(4)));
typedef float  f32x4  __attribute__((ext_vector_type(4)));

__device__ __forceinline__ float fsig(float x)  { return 1.0f / (1.0f + __expf(-x)); }
__device__ __forceinline__ float ftanh_(float x){ float e = __expf(2.0f * x); return 1.0f - 2.0f / (e + 1.0f); }

__device__ __forceinline__ bf16x8 bzero8() {
    bf16x8 z;
    #pragma unroll
    for (int q = 0; q < 8; q++) z[q] = (__bf16)0.f;
    return z;
}

// async 16B global -> LDS (dest = wave-uniform base + lane*16)
__device__ __forceinline__ void gload16(const __bf16* g, __bf16* l)
{
    __builtin_amdgcn_global_load_lds(
        (const __attribute__((address_space(1))) void*)g,
        (__attribute__((address_space(3))) void*)l, 16, 0, 0);
}

// ---------------- merged f32 -> bf16 conversions (one launch) ----------------
__global__ void cvt_all_k(const float* __restrict__ iouh_w, const float* __restrict__ fh_w,
                          const float* __restrict__ ioux_w, const float* __restrict__ fx_w,
                          const float* __restrict__ attnh_w, const float* __restrict__ inputs,
                          const float* __restrict__ Hmat,
                          __bf16* __restrict__ WzB, __bf16* __restrict__ WxB,
                          __bf16* __restrict__ W1H, __bf16* __restrict__ W2H,
                          __bf16* __restrict__ inpB, __bf16* __restrict__ HmatB)
{
    const size_t MM = (size_t)MD * MD;
    const size_t b0 = 3 * MM, b1 = 4 * MM, b2 = 7 * MM, b3 = 8 * MM;
    const size_t b4 = 9 * MM, b5 = 10 * MM, b6 = 12 * MM, b7 = 13 * MM;
    for (size_t idx = (size_t)blockIdx.x * 256 + threadIdx.x; idx < b7;
         idx += (size_t)gridDim.x * 256) {
        if (idx < b1) {
            WzB[idx] = (__bf16)((idx < b0) ? iouh_w[idx] : fh_w[idx - b0]);
        } else if (idx < b3) {
            size_t r = idx - b1;
            WxB[r] = (__bf16)((idx < b2) ? ioux_w[r] : fx_w[idx - b2]);
        } else if (idx < b4) {
            size_t r = idx - b3; size_t j = r >> 10, k = r & (MD - 1);
            W1H[r] = (__bf16)attnh_w[j * 2 * MD + k];
        } else if (idx < b5) {
            size_t r = idx - b4; size_t j = r >> 10, k = r & (MD - 1);
            W2H[r] = (__bf16)attnh_w[j * 2 * MD + MD + k];
        } else if (idx < b6) {
            size_t r = idx - b5;
            inpB[r] = (__bf16)inputs[r];
        } else {
            size_t r = idx - b6;
            HmatB[r] = (__bf16)Hmat[r];
        }
    }
}

__global__ void concat_bias_k(const float* __restrict__ a, const float* __restrict__ b,
                              float* __restrict__ dst)
{
    int i = blockIdx.x * 256 + threadIdx.x;
    dst[i] = (i < 3 * MD) ? a[i] : b[i - 3 * MD];
}

// epilogue modes:
//  0: (acc+bias)*scale (+X)
//  1: exp(clamp((acc+bias)*scale (+X), +-80))
//  2: FIN: C = add1[col] - acc + X ; C2 = X - acc ; C3 = bf16(X - acc)
// ---------------- bf16 MFMA NT GEMM, 128x128 tile ----------------
__global__ __launch_bounds__(256) void gemm_mfma(
    const __bf16* __restrict__ Ab, int lda,
    const __bf16* __restrict__ Wh,
    const float* __restrict__ bias,
    const float* __restrict__ X, int ldx, const float* __restrict__ add1,
    float* __restrict__ C, float* __restrict__ C2, __bf16* __restrict__ C3, int ldc,
    int I, int K, float scale, int epi)
{
    __shared__ __align__(16) __bf16 Ash[128][4][8];
    __shared__ __align__(16) __bf16 Bsh[128][4][8];
    const int tid = threadIdx.x;
    const int j0 = blockIdx.x * 128, i0 = blockIdx.y * 128;
    const int lane = tid & 63, wv = tid >> 6;
    const int wm = wv >> 1, wn = wv & 1;
    const int g = lane >> 4, fr = lane & 15;

    f32x4 acc[4][4];
    #pragma unroll
    for (int m = 0; m < 4; m++)
        #pragma unroll
        for (int n = 0; n < 4; n++)
            acc[m][n] = (f32x4){0.f, 0.f, 0.f, 0.f};

    const int srow = tid >> 2;
    const int sg   = tid & 3;
    int ar0 = i0 + srow;       if (ar0 >= I) ar0 = I - 1;
    int ar1 = i0 + srow + 64;  if (ar1 >= I) ar1 = I - 1;
    const __bf16* agp0 = Ab + (size_t)ar0 * lda + sg * 8;
    const __bf16* agp1 = Ab + (size_t)ar1 * lda + sg * 8;
    const __bf16* wgp0 = Wh + (size_t)(j0 + srow) * K + sg * 8;
    const __bf16* wgp1 = Wh + (size_t)(j0 + srow + 64) * K + sg * 8;
    __bf16* aD0 = &Ash[wv * 16][0][0];
    __bf16* aD1 = &Ash[64 + wv * 16][0][0];
    __bf16* bD0 = &Bsh[wv * 16][0][0];
    __bf16* bD1 = &Bsh[64 + wv * 16][0][0];

    for (int kt = 0; kt < K; kt += 32) {
        __syncthreads();
        gload16(agp0 + kt, aD0);
        gload16(agp1 + kt, aD1);
        gload16(wgp0 + kt, bD0);
        gload16(wgp1 + kt, bD1);
        __syncthreads();

        bf16x8 ah[4], bh[4];
        #pragma unroll
        for (int m = 0; m < 4; m++) ah[m] = *(bf16x8*)&Ash[wm * 64 + m * 16 + fr][g][0];
        #pragma unroll
        for (int n = 0; n < 4; n++) bh[n] = *(bf16x8*)&Bsh[wn * 64 + n * 16 + fr][g][0];
        #pragma unroll
        for (int m = 0; m < 4; m++)
            #pragma unroll
            for (int n = 0; n < 4; n++)
                acc[m][n] = __builtin_amdgcn_mfma_f32_16x16x32_bf16(ah[m], bh[n], acc[m][n], 0, 0, 0);
    }

    #pragma unroll
    for (int m = 0; m < 4; m++) {
        int rbase = i0 + wm * 64 + m * 16 + g * 4;
        #pragma unroll
        for (int nn = 0; nn < 4; nn++) {
            int col = j0 + wn * 64 + nn * 16 + fr;
            float b = bias ? bias[col] : 0.f;
            #pragma unroll
            for (int j = 0; j < 4; j++) {
                int r = rbase + j;
                if (r >= I) continue;
                float a = acc[m][nn][j];
                if (epi == 2) {
                    float hc = X[(size_t)r * ldx + col];
                    C[(size_t)r * ldc + col]  = add1[col] - a + hc;
                    float d = hc - a;
                    C2[(size_t)r * ldc + col] = d;
                    C3[(size_t)r * ldc + col] = (__bf16)d;
                } else {
                    float v = (a + b) * scale;
                    if (X) v += X[(size_t)r * ldx + col];
                    if (epi == 1) v = __expf(fminf(fmaxf(v, -80.f), 80.f));
                    C[(size_t)r * ldc + col] = v;
                }
            }
        }
    }
}

// ---------------- bf16 MFMA NT GEMM, 64x64 tile ----------------
__global__ __launch_bounds__(256) void gemm64_mfma(
    const __bf16* __restrict__ Ab, int lda,
    const __bf16* __restrict__ Wh,
    const float* __restrict__ bias,
    const float* __restrict__ X, int ldx, const float* __restrict__ add1,
    float* __restrict__ C, float* __restrict__ C2, __bf16* __restrict__ C3, int ldc,
    int I, int K, float scale, int epi)
{
    __shared__ __align__(16) __bf16 Ash[64][4][8];
    __shared__ __align__(16) __bf16 Bsh[64][4][8];
    const int tid = threadIdx.x;
    const int j0 = blockIdx.x * 64, i0 = blockIdx.y * 64;
    const int lane = tid & 63, wv = tid >> 6;
    const int wm = wv >> 1, wn = wv & 1;
    const int g = lane >> 4, fr = lane & 15;

    f32x4 acc[2][2];
    #pragma unroll
    for (int m = 0; m < 2; m++)
        #pragma unroll
        for (int n = 0; n < 2; n++)
            acc[m][n] = (f32x4){0.f, 0.f, 0.f, 0.f};

    const int srow = tid >> 2;
    const int sg   = tid & 3;
    int ar = i0 + srow;  if (ar >= I) ar = I - 1;
    const __bf16* agp = Ab + (size_t)ar * lda + sg * 8;
    const __bf16* wgp = Wh + (size_t)(j0 + srow) * K + sg * 8;
    __bf16* aD = &Ash[wv * 16][0][0];
    __bf16* bD = &Bsh[wv * 16][0][0];

    for (int kt = 0; kt < K; kt += 32) {
        __syncthreads();
        gload16(agp + kt, aD);
        gload16(wgp + kt, bD);
        __syncthreads();

        bf16x8 ah[2], bh[2];
        #pragma unroll
        for (int m = 0; m < 2; m++) ah[m] = *(bf16x8*)&Ash[wm * 32 + m * 16 + fr][g][0];
        #pragma unroll
        for (int n = 0; n < 2; n++) bh[n] = *(bf16x8*)&Bsh[wn * 32 + n * 16 + fr][g][0];
        #pragma unroll
        for (int m = 0; m < 2; m++)
            #pragma unroll
            for (int n = 0; n < 2; n++)
                acc[m][n] = __builtin_amdgcn_mfma_f32_16x16x32_bf16(ah[m], bh[n], acc[m][n], 0, 0, 0);
    }

    #pragma unroll
    for (int m = 0; m < 2; m++) {
        int rbase = i0 + wm * 32 + m * 16 + g * 4;
        #pragma unroll
        for (int nn = 0; nn < 2; nn++) {
            int col = j0 + wn * 32 + nn * 16 + fr;
            float b = bias ? bias[col] : 0.f;
            #pragma unroll
            for (int j = 0; j < 4; j++) {
                int r = rbase + j;
                if (r >= I) continue;
                float a = acc[m][nn][j];
                if (epi == 2) {
                    float hc = X[(size_t)r * ldx + col];
                    C[(size_t)r * ldc + col]  = add1[col] - a + hc;
                    float d = hc - a;
                    C2[(size_t)r * ldc + col] = d;
                    C3[(size_t)r * ldc + col] = (__bf16)d;
                } else {
                    float v = (a + b) * scale;
                    if (X) v += X[(size_t)r * ldx + col];
                    if (epi == 1) v = __expf(fminf(fmaxf(v, -80.f), 80.f));
                    C[(size_t)r * ldc + col] = v;
                }
            }
        }
    }
}

// ---------------- i-tiled batched GEMV (f32 A x bf16 W), tail I<=32 ----------------
// pointer-increment addressing: one v_add per pointer per k-step (no mad64 chains)
__global__ __launch_bounds__(256) void gemv16(
    const float* __restrict__ Af, int lda, int I,
    const __bf16* __restrict__ Wb, int ldw,
    const float* __restrict__ bias,
    const float* __restrict__ X, int ldx, const float* __restrict__ add1,
    float* __restrict__ C, float* __restrict__ C2, __bf16* __restrict__ C3, int ldc,
    int K, float scale, int epi)
{
    const int wv = threadIdx.x >> 6, lane = threadIdx.x & 63;
    const int j = blockIdx.x * 4 + wv;
    const int i0 = blockIdx.y * 16;
    const int nI = (I - i0 < 16) ? (I - i0) : 16;
    float acc[16];
    #pragma unroll
    for (int i = 0; i < 16; i++) acc[i] = 0.0f;
    const __bf16* wp = Wb + (size_t)j * ldw + lane * 4;
    const float*  ap = Af + (size_t)i0 * lda + lane * 4;
    for (int k = lane * 4; k < K; k += 256, wp += 256, ap += 256) {
        bf16x4 w4 = *(const bf16x4*)wp;
        float w0 = (float)w4[0], w1 = (float)w4[1], w2 = (float)w4[2], w3 = (float)w4[3];
        const float* a = ap;
        #pragma unroll
        for (int i = 0; i < 16; i++, a += lda) {
            if (i < nI) {
                float4 a4 = *(const float4*)a;
                acc[i] += a4.x * w0 + a4.y * w1 + a4.z * w2 + a4.w * w3;
            }
        }
    }
    #pragma unroll
    for (int i = 0; i < 16; i++) {
        if (i < nI) {
            float s = acc[i];
            #pragma unroll
            for (int off = 32; off >= 1; off >>= 1) s += __shfl_xor(s, off);
            if (lane == 0) {
                int r = i0 + i;
                if (epi == 2) {
                    float hc = X[(size_t)r * ldx + j];
                    C[(size_t)r * ldc + j]  = add1[j] - s + hc;
                    float d = hc - s;
                    C2[(size_t)r * ldc + j] = d;
                    C3[(size_t)r * ldc + j] = (__bf16)d;
                } else {
                    float v = (s + (bias ? bias[j] : 0.f)) * scale;
                    if (X) v += X[(size_t)r * ldx + j];
                    if (epi == 1) v = __expf(fminf(fmaxf(v, -80.f), 80.f));
                    C[(size_t)r * ldc + j] = v;
                }
            }
        }
    }
}

// ---------------- exact f32 GEMV (HsumWz precompute only, I=1) ----------------
__global__ __launch_bounds__(256) void gemvHsum(
    const float* __restrict__ Af,
    const float* __restrict__ Wf, int ldw,
    float* __restrict__ C, int K)
{
    const int wv = threadIdx.x >> 6, lane = threadIdx.x & 63;
    const int j = blockIdx.x * 4 + wv;
    float a = 0.f;
    for (int k = lane * 4; k < K; k += 256) {
        float4 w4 = *(const float4*)(Wf + (size_t)j * ldw + k);
        float4 a4 = *(const float4*)(Af + k);
        a += a4.x * w4.x + a4.y * w4.y + a4.z * w4.z + a4.w * w4.w;
    }
    #pragma unroll
    for (int off = 32; off >= 1; off >>= 1) a += __shfl_xor(a, off);
    if (lane == 0) C[j] = a;
}

// ---------------- attention scores via exp tables ----------------
template<int LTILE>
__global__ __launch_bounds__(512) void attn_s(
    int B, const float* __restrict__ Eh,
    const float* __restrict__ EH,
    const float* __restrict__ s_wa_sum,
    const float* __restrict__ Wa,
    float* __restrict__ S)
{
    __shared__ float s_e[8][MD];
    __shared__ float s_wa[MD];
    const int lt = blockIdx.x * LTILE;
    const int b0 = blockIdx.y * 8;
    const int nt = (B - b0 < 8) ? (B - b0) : 8;
    for (int idx = threadIdx.x; idx < MD; idx += 512) s_wa[idx] = Wa[idx];
    for (int i = 0; i < nt; i++)
        for (int idx = threadIdx.x; idx < MD; idx += 512)
            s_e[i][idx] = Eh[(size_t)(b0 + i) * MD + idx];
    __syncthreads();
    const int wv = threadIdx.x >> 6, lane = threadIdx.x & 63;
    const float swa = s_wa_sum[0];
    if (LTILE >= 16) {
        for (int l = lt + wv; l < lt + LTILE; l += 16) {
            float accA[8] = {}, accB[8] = {};
            const float* erA = EH + (size_t)l * MD;
            const float* erB = EH + (size_t)(l + 8) * MD;
            for (int mc = 0; mc < MD; mc += 256) {
                const int m = mc + lane * 4;
                float4 evA = *(const float4*)(erA + m);
                float4 evB = *(const float4*)(erB + m);
                float4 wa4 = *(const float4*)&s_wa[m];
                #pragma unroll
                for (int i = 0; i < 8; i++) {
                    if (i < nt) {
                        float4 se = *(const float4*)&s_e[i][m];
                        accA[i] = fmaf(wa4.x, __builtin_amdgcn_rcpf(fmaf(se.x, evA.x, 1.0f)), accA[i]);
                        accA[i] = fmaf(wa4.y, __builtin_amdgcn_rcpf(fmaf(se.y, evA.y, 1.0f)), accA[i]);
                        accA[i] = fmaf(wa4.z, __builtin_amdgcn_rcpf(fmaf(se.z, evA.z, 1.0f)), accA[i]);
                        accA[i] = fmaf(wa4.w, __builtin_amdgcn_rcpf(fmaf(se.w, evA.w, 1.0f)), accA[i]);
                        accB[i] = fmaf(wa4.x, __builtin_amdgcn_rcpf(fmaf(se.x, evB.x, 1.0f)), accB[i]);
                        accB[i] = fmaf(wa4.y, __builtin_amdgcn_rcpf(fmaf(se.y, evB.y, 1.0f)), accB[i]);
                        accB[i] = fmaf(wa4.z, __builtin_amdgcn_rcpf(fmaf(se.z, evB.z, 1.0f)), accB[i]);
                        accB[i] = fmaf(wa4.w, __builtin_amdgcn_rcpf(fmaf(se.w, evB.w, 1.0f)), accB[i]);
                    }
                }
            }
            #pragma unroll
            for (int i = 0; i < 8; i++) {
                if (i < nt) {
                    float vA = accA[i], vB = accB[i];
                    #pragma unroll
                    for (int off = 32; off >= 1; off >>= 1) {
                        vA += __shfl_xor(vA, off);
                        vB += __shfl_xor(vB, off);
                    }
                    if (lane == 0) {
                        S[(size_t)(b0 + i) * LD + l]     = swa - 2.0f * vA;
                        S[(size_t)(b0 + i) * LD + l + 8] = swa - 2.0f * vB;
                    }
                }
            }
        }
    } else {
        for (int l = lt + wv; l < lt + LTILE; l += 8) {
            float acc[8] = {};
            const float* er = EH + (size_t)l * MD;
            for (int mc = 0; mc < MD; mc += 256) {
                const int m = mc + lane * 4;
                float4 ev  = *(const float4*)(er + m);
                float4 wa4 = *(const float4*)&s_wa[m];
                #pragma unroll
                for (int i = 0; i < 8; i++) {
                    if (i < nt) {
                        float4 se = *(const float4*)&s_e[i][m];
                        acc[i] = fmaf(wa4.x, __builtin_amdgcn_rcpf(fmaf(se.x, ev.x, 1.0f)), acc[i]);
                        acc[i] = fmaf(wa4.y, __builtin_amdgcn_rcpf(fmaf(se.y, ev.y, 1.0f)), acc[i]);
                        acc[i] = fmaf(wa4.z, __builtin_amdgcn_rcpf(fmaf(se.z, ev.z, 1.0f)), acc[i]);
                        acc[i] = fmaf(wa4.w, __builtin_amdgcn_rcpf(fmaf(se.w, ev.w, 1.0f)), acc[i]);
                    }
                }
            }
            #pragma unroll
            for (int i = 0; i < 8; i++) {
                if (i < nt) {
                    float v = acc[i];
                    #pragma unroll
                    for (int off = 32; off >= 1; off >>= 1) v += __shfl_xor(v, off);
                    if (lane == 0) S[(size_t)(b0 + i) * LD + l] = swa - 2.0f * v;
                }
            }
        }
    }
}

// ---------------- softmax (f32 + bf16 copies of P) ----------------
__global__ __launch_bounds__(256) void softmax_rows(float* __restrict__ S, __bf16* __restrict__ Sb)
{
    float* row = S + (size_t)blockIdx.x * LD;
    __bf16* rb = Sb + (size_t)blockIdx.x * LD;
    const int tid = threadIdx.x;
    const int wv = tid >> 6, lane = tid & 63;
    float v0 = row[tid], v1 = row[tid + 256], v2 = row[tid + 512], v3 = row[tid + 768];
    float mx = fmaxf(fmaxf(v0, v1), fmaxf(v2, v3));
    #pragma unroll
    for (int off = 32; off >= 1; off >>= 1) mx = fmaxf(mx, __shfl_xor(mx, off));
    __shared__ float r1[4], r2[4];
    if (lane == 0) r1[wv] = mx;
    __syncthreads();
    mx = fmaxf(fmaxf(r1[0], r1[1]), fmaxf(r1[2], r1[3]));
    float e0 = __expf(v0 - mx), e1 = __expf(v1 - mx), e2 = __expf(v2 - mx), e3 = __expf(v3 - mx);
    float sm = e0 + e1 + e2 + e3;
    #pragma unroll
    for (int off = 32; off >= 1; off >>= 1) sm += __shfl_xor(sm, off);
    if (lane == 0) r2[wv] = sm;
    __syncthreads();
    sm = r2[0] + r2[1] + r2[2] + r2[3];
    float inv = 1.0f / sm;
    float p0 = e0 * inv, p1 = e1 * inv, p2 = e2 * inv, p3 = e3 * inv;
    row[tid] = p0; row[tid + 256] = p1; row[tid + 512] = p2; row[tid + 768] = p3;
    rb[tid] = (__bf16)p0; rb[tid + 256] = (__bf16)p1;
    rb[tid + 512] = (__bf16)p2; rb[tid + 768] = (__bf16)p3;
}

// ---------------- cell finish ----------------
__global__ void cell_finish_k(const int* __restrict__ children, int t0,
    const float* __restrict__ Z, const float* __restrict__ HsumWz,
    const float* __restrict__ iouh_b, const float* __restrict__ fh_b,
    const float* __restrict__ x_all,
    float* __restrict__ Cmat, float* __restrict__ hcell, __bf16* __restrict__ hcellB)
{
    int b = blockIdx.y;
    int m = blockIdx.x * 256 + threadIdx.x;
    int t = t0 + b;
    int c0 = children[2 * t], c1 = children[2 * t + 1];
    float cnt = (float)((c0 >= 0) + (c1 >= 0));
    const float* z0 = (c0 >= 0) ? Z + (size_t)c0 * JZ : nullptr;
    const float* z1 = (c1 >= 0) ? Z + (size_t)c1 * JZ : nullptr;
    const float* xr = x_all + (size_t)t * JZ;

    float zi = 0.f, zo = 0.f, zu = 0.f;
    if (z0) { zi += z0[m]; zo += z0[MD + m]; zu += z0[2 * MD + m]; }
    if (z1) { zi += z1[m]; zo += z1[MD + m]; zu += z1[2 * MD + m]; }
    float iv = fsig (zi + cnt * HsumWz[m]           + iouh_b[m]           + xr[m]);
    float ov = fsig (zo + cnt * HsumWz[MD + m]      + iouh_b[MD + m]      + xr[MD + m]);
    float uv = ftanh_(zu + cnt * HsumWz[2 * MD + m] + iouh_b[2 * MD + m]  + xr[2 * MD + m]);

    float hwf = HsumWz[3 * MD + m] + fh_b[m] + xr[3 * MD + m];
    float c = iv * uv;
    if (c0 >= 0) c += fsig(z0[3 * MD + m] + hwf) * Cmat[(size_t)c0 * MD + m];
    if (c1 >= 0) c += fsig(z1[3 * MD + m] + hwf) * Cmat[(size_t)c1 * MD + m];
    Cmat[(size_t)t * MD + m] = c;
    float h = ov * ftanh_(c);
    hcell[(size_t)b * MD + m] = h;
    hcellB[(size_t)b * MD + m] = (__bf16)h;
}

// ---------------- misc precompute ----------------
__global__ void colsum_part_k(const float* __restrict__ H, float* __restrict__ part)
{
    int m = blockIdx.x * 256 + threadIdx.x;
    int lb = blockIdx.y;
    float s = 0.f;
    for (int l = lb * 64; l < lb * 64 + 64; l++) s += H[(size_t)l * MD + m];
    part[(size_t)lb * MD + m] = s;
}

__global__ void colsum_reduce_k(const float* __restrict__ part, float* __restrict__ Hsum)
{
    int m = blockIdx.x * 256 + threadIdx.x;
    float s = 0.f;
    for (int lb = 0; lb < 16; lb++) s += part[(size_t)lb * MD + m];
    Hsum[m] = s;
}

__global__ void transpose2_k(const float* __restrict__ H,
                             float* __restrict__ Ht, __bf16* __restrict__ Htb)
{
    __shared__ float tile[32][33];
    int mb = blockIdx.x * 32, lb = blockIdx.y * 32;
    int tx = threadIdx.x, ty = threadIdx.y;
    #pragma unroll
    for (int jj = 0; jj < 4; jj++)
        tile[ty + jj * 8][tx] = H[(size_t)(lb + ty + jj * 8) * MD + mb + tx];
    __syncthreads();
    #pragma unroll
    for (int jj = 0; jj < 4; jj++) {
        float v = tile[tx][ty + jj * 8];
        size_t idx = (size_t)(mb + ty + jj * 8) * LD + lb + tx;
        Ht[idx]  = v;
        Htb[idx] = (__bf16)v;
    }
}

__global__ void sumwa_k(const float* __restrict__ Wa, float* __restrict__ out)
{
    int tid = threadIdx.x;
    float v = Wa[tid] + Wa[tid + 256] + Wa[tid + 512] + Wa[tid + 768];
    #pragma unroll
    for (int off = 32; off >= 1; off >>= 1) v += __shfl_xor(v, off);
    __shared__ float r[4];
    if ((tid & 63) == 0) r[tid >> 6] = v;
    __syncthreads();
    if (tid == 0) out[0] = r[0] + r[1] + r[2] + r[3];
}

__global__ void final_copy_k(const float* __restrict__ Cmat, float* __restrict__ out)
{
    int m = blockIdx.x * 256 + threadIdx.x;
    out[m] = Cmat[m];              // C[0]
    out[1024 + m] = out[2048 + m]; // Hs[0]
}

// ---------------- dispatcher ----------------
static inline void mmx(const __bf16* Ab, const float* Af, int lda, int I,
                       const __bf16* Wb,
                       const float* bias, const float* X, int ldx, const float* add1,
                       float* C, float* C2, __bf16* C3, int ldc, int J, int K,
                       float scale, int epi, hipStream_t s)
{
    if (I <= 32) {
        gemv16<<<dim3(J / 4, (I + 15) / 16), 256, 0, s>>>(
            Af, lda, I, Wb, K, bias, X, ldx, add1, C, C2, C3, ldc, K, scale, epi);
    } else {
        int b128 = (J / 128) * ((I + 127) / 128);
        if (b128 >= 192)
            gemm_mfma<<<dim3(J / 128, (I + 127) / 128), 256, 0, s>>>(
                Ab, lda, Wb, bias, X, ldx, add1, C, C2, C3, ldc, I, K, scale, epi);
        else
            gemm64_mfma<<<dim3(J / 64, (I + 63) / 64), 256, 0, s>>>(
                Ab, lda, Wb, bias, X, ldx, add1, C, C2, C3, ldc, I, K, scale, epi);
    }
}

extern "C" void kernel_launch(void* const* d_in, const int* in_sizes, int n_in,
                              void* d_out, int out_size, void* d_ws, size_t ws_size,
                              hipStream_t stream)
{
    const float* inputs   = (const float*)d_in[0];
    const float* Hmat     = (const float*)d_in[1];
    const int*   children = (const int*)d_in[2];
    const float* ioux_w   = (const float*)d_in[3];
    const float* ioux_b   = (const float*)d_in[4];
    const float* iouh_w   = (const float*)d_in[5];
    const float* iouh_b   = (const float*)d_in[6];
    const float* fx_w     = (const float*)d_in[7];
    const float* fx_b     = (const float*)d_in[8];
    const float* fh_w     = (const float*)d_in[9];
    const float* fh_b     = (const float*)d_in[10];
    const float* Wa       = (const float*)d_in[11];
    const float* attnh_w  = (const float*)d_in[12];
    const float* attnh_b  = (const float*)d_in[13];

    float* out = (float*)d_out;
    float* Hs  = out + 2048;   // Hs (N*M) lives in d_out

    // ---- workspace layout ----
    float* p = (float*)d_ws;
    float* x_all   = p;  p += (size_t)ND * JZ;
    float* Zbuf    = p;  p += (size_t)ND * JZ;
    float* EHbuf   = p;  p += (size_t)LD * MD;
    float* Ht      = p;  p += (size_t)MD * LD;
    float* Cmat    = p;  p += (size_t)ND * MD;
    float* Hdelta  = p;  p += (size_t)ND * MD;
    float* hcell   = p;  p += (size_t)1024 * MD;
    float* Ehbuf   = p;  p += (size_t)1024 * MD;
    float* Sbuf    = p;  p += (size_t)1024 * LD;
    float* Hsum    = p;  p += MD;
    float* part16  = p;  p += 16 * MD;
    float* S_wa    = p;  p += 8;
    float* HsumWz  = p;  p += JZ;
    float* bx      = p;  p += JZ;
    __bf16* q = (__bf16*)p;
    __bf16* WzB    = q; q += (size_t)JZ * MD;
    __bf16* WxB    = q; q += (size_t)JZ * MD;
    __bf16* W1H    = q; q += (size_t)MD * MD;
    __bf16* W2H    = q; q += (size_t)MD * MD;
    __bf16* HtH    = q; q += (size_t)MD * LD;
    __bf16* inpB   = q; q += (size_t)ND * MD;
    __bf16* HmatB  = q; q += (size_t)LD * MD;
    __bf16* SbB    = q; q += (size_t)1024 * LD;
    __bf16* HdB    = q; q += (size_t)ND * MD;
    __bf16* hcellB = q; q += (size_t)1024 * MD;

    // ---- one-time conversions & precomputes ----
    cvt_all_k<<<2048, 256, 0, stream>>>(iouh_w, fh_w, ioux_w, fx_w, attnh_w, inputs, Hmat,
                                        WzB, WxB, W1H, W2H, inpB, HmatB);
    concat_bias_k<<<JZ / 256, 256, 0, stream>>>(ioux_b, fx_b, bx);
    transpose2_k<<<dim3(32, 32), dim3(32, 8), 0, stream>>>(Hmat, Ht, HtH);
    sumwa_k<<<1, 256, 0, stream>>>(Wa, S_wa);
    colsum_part_k<<<dim3(4, 16), 256, 0, stream>>>(Hmat, part16);
    colsum_reduce_k<<<4, 256, 0, stream>>>(part16, Hsum);
    gemvHsum<<<(3 * MD) / 4, 256, 0, stream>>>(Hsum, iouh_w, MD, HsumWz, MD);
    gemvHsum<<<MD / 4, 256, 0, stream>>>(Hsum, fh_w, MD, HsumWz + 3 * MD, MD);

    // x_all = inputs @ [ioux_w; fx_w]^T + [ioux_b; fx_b]
    mmx(inpB, inputs, MD, ND, WxB, bx, nullptr, 0, nullptr,
        x_all, nullptr, nullptr, JZ, JZ, MD, 1.0f, 0, stream);
    // EH = exp(2*(H@W2^T + attnh_b))
    mmx(HmatB, Hmat, MD, LD, W2H, attnh_b, nullptr, 0, nullptr,
        EHbuf, nullptr, nullptr, MD, MD, MD, 2.0f, 1, stream);

    static const int lv_t0[12] = {2047, 1023, 511, 255, 127, 63, 31, 15, 7, 3, 1, 0};
    static const int lv_B [12] = {1, 1024, 512, 256, 128, 64, 32, 16, 8, 4, 2, 1};

    // ---- level-parallel tree scan (deepest first), uniform 6-kernel pipeline ----
    for (int li = 0; li < 12; li++) {
        int t0 = lv_t0[li], B = lv_B[li];
        cell_finish_k<<<dim3(4, B), 256, 0, stream>>>(children, t0, Zbuf, HsumWz,
                                                      iouh_b, fh_b, x_all, Cmat, hcell, hcellB);
        // Eh = exp(2*hcell@W1^T)
        mmx(hcellB, hcell, MD, B, W1H, nullptr, nullptr, 0, nullptr,
            Ehbuf, nullptr, nullptr, MD, MD, MD, 2.0f, 1, stream);
        if (B >= 128)
            attn_s<64><<<dim3(LD / 64, B / 8), 512, 0, stream>>>(B, Ehbuf, EHbuf, S_wa, Wa, Sbuf);
        else if (B >= 16)
            attn_s<16><<<dim3(LD / 16, (B + 7) / 8), 512, 0, stream>>>(B, Ehbuf, EHbuf, S_wa, Wa, Sbuf);
        else
            attn_s<8><<<dim3(LD / 8, 1), 512, 0, stream>>>(B, Ehbuf, EHbuf, S_wa, Wa, Sbuf);
        softmax_rows<<<B, 256, 0, stream>>>(Sbuf, SbB);
        // FIN: Hs = Hsum - p@H + hcell ; Hdelta/HdB = hcell - p@H
        mmx(SbB, Sbuf, LD, B, HtH, nullptr, hcell, MD, Hsum,
            Hs + (size_t)t0 * MD, Hdelta + (size_t)t0 * MD, HdB + (size_t)t0 * MD,
            MD, MD, LD, 1.0f, 2, stream);
        // Z[t] = Hdelta[t] @ [iouh_w; fh_w]^T  (not needed for root)
        if (li < 11)
            mmx(HdB + (size_t)t0 * MD, Hdelta + (size_t)t0 * MD, MD, B, WzB,
                nullptr, nullptr, 0, nullptr,
                Zbuf + (size_t)t0 * JZ, nullptr, nullptr, JZ, JZ, MD, 1.0f, 0, stream);
    }
    final_copy_k<<<4, 256, 0, stream>>>(Cmat, out);
}